// Round 1
// baseline (922.412 us; speedup 1.0000x reference)
//
#include <hip/hip_runtime.h>
#include <math.h>

#define N_NODES 10000
#define B_SZ 2
#define T_STEPS 8
#define M_COLS 16                  // B*T
#define C_HID 64
#define NM (N_NODES*M_COLS)        // 160000 rows for layer GEMMs
#define BN (B_SZ*N_NODES)          // 20000 GRU rows
#define F1024 (M_COLS*C_HID)       // 1024 features per node in layer-2 spmm

// ---------------- CSR build ----------------
__global__ __launch_bounds__(256) void k_count(const int* __restrict__ dst, int* __restrict__ cnt, int E) {
  int e = blockIdx.x*256 + threadIdx.x;
  if (e < E) atomicAdd(&cnt[dst[e]], 1);
}

__global__ __launch_bounds__(256) void k_scan(const int* __restrict__ cnt, int* __restrict__ rowp, int n) {
  __shared__ int sd[256];
  __shared__ int s_run;
  if (threadIdx.x == 0) s_run = 0;
  __syncthreads();
  for (int base = 0; base < n; base += 256) {
    int i = base + (int)threadIdx.x;
    int v = (i < n) ? cnt[i] : 0;
    sd[threadIdx.x] = v;
    __syncthreads();
    for (int off = 1; off < 256; off <<= 1) {
      int t = (threadIdx.x >= (unsigned)off) ? sd[threadIdx.x - off] : 0;
      __syncthreads();
      sd[threadIdx.x] += t;
      __syncthreads();
    }
    int run = s_run;
    if (i < n) rowp[i] = run + sd[threadIdx.x] - v;   // exclusive prefix
    __syncthreads();
    if (threadIdx.x == 255) s_run = run + sd[255];
    __syncthreads();
  }
  if (threadIdx.x == 0) rowp[n] = s_run;
}

__global__ __launch_bounds__(256) void k_fill(const int* __restrict__ src, const int* __restrict__ dst,
                                              const float* __restrict__ val, const int* __restrict__ rowp,
                                              int* __restrict__ cur, int* __restrict__ csrs,
                                              float* __restrict__ csrv, int E) {
  int e = blockIdx.x*256 + threadIdx.x;
  if (e >= E) return;
  int d = dst[e];
  int p = atomicAdd(&cur[d], 1);
  int slot = rowp[d] + p;
  csrs[slot] = src[e];
  csrv[slot] = val[e];
}

// ---------------- layer 1 ----------------
__global__ __launch_bounds__(256) void k_x2h(const float* __restrict__ x, float* __restrict__ Z0) {
  int i = blockIdx.x*256 + threadIdx.x;
  if (i >= NM) return;
  int n = i >> 4, m = i & 15;
  int b = m >> 3, t = m & 7;
  Z0[i] = x[b*(N_NODES*T_STEPS) + n*T_STEPS + t];
}

__global__ __launch_bounds__(256) void k_spmm16(const float* __restrict__ Zin, float* __restrict__ Zout,
                                                const int* __restrict__ rowp, const int* __restrict__ csrs,
                                                const float* __restrict__ csrv) {
  int i = blockIdx.x*256 + threadIdx.x;
  if (i >= NM) return;
  int n = i >> 4, m = i & 15;
  int s = rowp[n], e = rowp[n+1];
  float acc = 0.f;
  for (int k = s; k < e; ++k)
    acc = fmaf(csrv[k], Zin[csrs[k]*16 + m], acc);
  Zout[i] = acc;
}

__global__ __launch_bounds__(256) void k_layer1(const float* __restrict__ Z0, const float* __restrict__ Z1,
                                                const float* __restrict__ Z2, const float* __restrict__ W1,
                                                const float* __restrict__ b1, float* __restrict__ H1) {
  int i = blockIdx.x*256 + threadIdx.x;      // exactly NM*64 threads
  int c = i & 63, nm = i >> 6;
  float v = fmaf(Z0[nm], W1[c], fmaf(Z1[nm], W1[64+c], fmaf(Z2[nm], W1[128+c], b1[c])));
  H1[i] = v > 0.f ? v : 0.f;
}

// ---------------- layer 2 ----------------
__global__ __launch_bounds__(256) void k_spmm1024(const float* __restrict__ Zin, float* __restrict__ Zout,
                                                  const int* __restrict__ rowp, const int* __restrict__ csrs,
                                                  const float* __restrict__ csrv) {
  int n = blockIdx.x;
  int tid = threadIdx.x;
  int s = rowp[n], e = rowp[n+1];
  float4 acc = {0.f, 0.f, 0.f, 0.f};
  for (int k = s; k < e; ++k) {
    float v = csrv[k];
    const float4* p = reinterpret_cast<const float4*>(Zin + (size_t)csrs[k]*F1024);
    float4 z = p[tid];
    acc.x = fmaf(v, z.x, acc.x); acc.y = fmaf(v, z.y, acc.y);
    acc.z = fmaf(v, z.z, acc.z); acc.w = fmaf(v, z.w, acc.w);
  }
  reinterpret_cast<float4*>(Zout + (size_t)n*F1024)[tid] = acc;
}

// out[row][c0..c0+31] (+)= Z[row][:] @ W[64][64], weights via uniform (scalar) loads.
__global__ __launch_bounds__(256) void k_dense64(const float* __restrict__ Z, const float* __restrict__ W,
                                                 const float* __restrict__ b2, float* __restrict__ out, int mode) {
  int row = blockIdx.x*256 + threadIdx.x;    // exactly NM
  int c0 = blockIdx.y * 32;
  const float4* zp = reinterpret_cast<const float4*>(Z + (size_t)row*64);
  float acc[32];
#pragma unroll
  for (int u = 0; u < 32; ++u) acc[u] = 0.f;
  for (int jc = 0; jc < 8; ++jc) {
    float4 v0 = zp[jc*2], v1 = zp[jc*2+1];
    float z[8] = {v0.x, v0.y, v0.z, v0.w, v1.x, v1.y, v1.z, v1.w};
#pragma unroll
    for (int j = 0; j < 8; ++j)
#pragma unroll
      for (int u = 0; u < 32; ++u)
        acc[u] = fmaf(z[j], W[(jc*8+j)*64 + c0 + u], acc[u]);
  }
  float* op = out + (size_t)row*64 + c0;
  if (mode == 0) {
#pragma unroll
    for (int u = 0; u < 32; ++u) op[u] = acc[u];
  } else if (mode == 1) {
#pragma unroll
    for (int u = 0; u < 32; ++u) op[u] += acc[u];
  } else {
#pragma unroll
    for (int u = 0; u < 32; ++u) {
      float val = op[u] + acc[u] + b2[c0 + u];
      op[u] = val > 0.f ? val : 0.f;
    }
  }
}

// ---------------- GRU ----------------
// gates layout per row (256 floats): [0:64) r (x+h+both biases), [64:128) z,
// [128:192) nx (+b_ih), [192:256) nh (+b_hh)
__global__ __launch_bounds__(256) void k_gates(const float* __restrict__ H2, const float* __restrict__ hprev,
                                               const float* __restrict__ Wih, const float* __restrict__ Whh,
                                               const float* __restrict__ bih, const float* __restrict__ bhh,
                                               float* __restrict__ g, int t) {
  int row = blockIdx.x*256 + threadIdx.x;
  int gc = blockIdx.y;                        // 0..15 (uniform)
  bool act = row < BN;
  int rr = act ? row : 0;
  int b = rr / N_NODES, n = rr % N_NODES;
  const bool needx = (gc < 12);
  const bool needh = (gc < 8) || (gc >= 12);
  float xv[64], hv[64];
  if (needx) {
    const float4* xp = reinterpret_cast<const float4*>(H2 + (size_t)n*F1024 + (b*T_STEPS + t)*64);
#pragma unroll
    for (int q = 0; q < 16; ++q) {
      float4 v = xp[q];
      xv[4*q] = v.x; xv[4*q+1] = v.y; xv[4*q+2] = v.z; xv[4*q+3] = v.w;
    }
  }
  if (needh) {
    const float4* hp = reinterpret_cast<const float4*>(hprev + (size_t)rr*64);
#pragma unroll
    for (int q = 0; q < 16; ++q) {
      float4 v = hp[q];
      hv[4*q] = v.x; hv[4*q+1] = v.y; hv[4*q+2] = v.z; hv[4*q+3] = v.w;
    }
  }
  float acc[16];
  if (gc < 8) {                                // r,z gates: x and h parts + both biases
    int g0 = gc*16;
#pragma unroll
    for (int u = 0; u < 16; ++u) acc[u] = bih[g0+u] + bhh[g0+u];
#pragma unroll
    for (int j = 0; j < 64; ++j)
#pragma unroll
      for (int u = 0; u < 16; ++u)
        acc[u] = fmaf(xv[j], Wih[(g0+u)*64 + j], fmaf(hv[j], Whh[(g0+u)*64 + j], acc[u]));
    if (act) {
      float4* gp = reinterpret_cast<float4*>(g + (size_t)row*256 + g0);
#pragma unroll
      for (int q = 0; q < 4; ++q) gp[q] = make_float4(acc[4*q], acc[4*q+1], acc[4*q+2], acc[4*q+3]);
    }
  } else if (gc < 12) {                        // nx = x@Wih_n + b_ih_n
    int g0 = 128 + (gc-8)*16;
#pragma unroll
    for (int u = 0; u < 16; ++u) acc[u] = bih[g0+u];
#pragma unroll
    for (int j = 0; j < 64; ++j)
#pragma unroll
      for (int u = 0; u < 16; ++u)
        acc[u] = fmaf(xv[j], Wih[(g0+u)*64 + j], acc[u]);
    if (act) {
      float4* gp = reinterpret_cast<float4*>(g + (size_t)row*256 + g0);
#pragma unroll
      for (int q = 0; q < 4; ++q) gp[q] = make_float4(acc[4*q], acc[4*q+1], acc[4*q+2], acc[4*q+3]);
    }
  } else {                                     // nh = h@Whh_n + b_hh_n → slot 192..256
    int g0 = 128 + (gc-12)*16;
#pragma unroll
    for (int u = 0; u < 16; ++u) acc[u] = bhh[g0+u];
#pragma unroll
    for (int j = 0; j < 64; ++j)
#pragma unroll
      for (int u = 0; u < 16; ++u)
        acc[u] = fmaf(hv[j], Whh[(g0+u)*64 + j], acc[u]);
    if (act) {
      float4* gp = reinterpret_cast<float4*>(g + (size_t)row*256 + 64 + g0);
#pragma unroll
      for (int q = 0; q < 4; ++q) gp[q] = make_float4(acc[4*q], acc[4*q+1], acc[4*q+2], acc[4*q+3]);
    }
  }
}

__global__ __launch_bounds__(256) void k_gru_pt(const float* __restrict__ g, const float* __restrict__ hprev,
                                                float* __restrict__ hnext) {
  int i = blockIdx.x*256 + threadIdx.x;       // exactly BN*64
  int row = i >> 6, l = i & 63;
  const float* gr = g + (size_t)row*256;
  float r = 1.f / (1.f + expf(-gr[l]));
  float z = 1.f / (1.f + expf(-gr[64+l]));
  float nn = tanhf(gr[128+l] + r*gr[192+l]);
  float h = hprev[i];
  hnext[i] = (1.f - z)*nn + z*h;
}

__global__ __launch_bounds__(256) void k_head(const float* __restrict__ h, const float* __restrict__ Wh,
                                              const float* __restrict__ bh, float* __restrict__ y) {
  int w = threadIdx.x >> 6, l = threadIdx.x & 63;
  int row = blockIdx.x*4 + w;                 // 5000 blocks * 4 rows = BN
  float v = h[(size_t)row*64 + l] * Wh[l];
#pragma unroll
  for (int off = 32; off > 0; off >>= 1)
    v += __shfl_xor(v, off, 64);
  if (l == 0) y[row] = v + bh[0];
}

extern "C" void kernel_launch(void* const* d_in, const int* in_sizes, int n_in,
                              void* d_out, int out_size, void* d_ws, size_t ws_size,
                              hipStream_t stream) {
  const float* x    = (const float*)d_in[0];
  const int*   esrc = (const int*)d_in[1];
  const int*   edst = (const int*)d_in[2];
  const float* eval = (const float*)d_in[3];
  const float* W1   = (const float*)d_in[4];
  const float* b1   = (const float*)d_in[5];
  const float* W2   = (const float*)d_in[6];
  const float* b2   = (const float*)d_in[7];
  const float* Wih  = (const float*)d_in[8];
  const float* Whh  = (const float*)d_in[9];
  const float* bih  = (const float*)d_in[10];
  const float* bhh  = (const float*)d_in[11];
  const float* Whead= (const float*)d_in[12];
  const float* bhead= (const float*)d_in[13];
  int E = in_sizes[1];
  float* y = (float*)d_out;

  // workspace carve-up (fp32), ~136.4 MB total
  float* H1   = (float*)d_ws;
  float* ZB   = H1 + 10240000;       // also reused as GRU gates buffer (needs 5.12M)
  float* OUT2 = ZB + 10240000;
  float* Z0   = OUT2 + 10240000;
  float* Z1   = Z0 + NM;
  float* Z2   = Z1 + NM;
  float* ha   = Z2 + NM;
  float* hb   = ha + (size_t)BN*64;
  int*   rowp = (int*)(hb + (size_t)BN*64);
  int*   cnt  = rowp + (N_NODES + 1);
  int*   csrs = cnt + N_NODES;
  float* csrv = (float*)(csrs + E);

  int eb = (E + 255) / 256;

  // CSR build (by dst)
  hipMemsetAsync(cnt, 0, N_NODES*sizeof(int), stream);
  k_count<<<eb, 256, 0, stream>>>(edst, cnt, E);
  k_scan<<<1, 256, 0, stream>>>(cnt, rowp, N_NODES);
  hipMemsetAsync(cnt, 0, N_NODES*sizeof(int), stream);
  k_fill<<<eb, 256, 0, stream>>>(esrc, edst, eval, rowp, cnt, csrs, csrv, E);

  // layer 1 (F_in = 1): Z0, A Z0, A^2 Z0 then rank-1 expansion to HID
  k_x2h<<<625, 256, 0, stream>>>(x, Z0);
  k_spmm16<<<625, 256, 0, stream>>>(Z0, Z1, rowp, csrs, csrv);
  k_spmm16<<<625, 256, 0, stream>>>(Z1, Z2, rowp, csrs, csrv);
  k_layer1<<<40000, 256, 0, stream>>>(Z0, Z1, Z2, W1, b1, H1);

  // layer 2: OUT2 = relu(H1 W0 + (A H1) W1 + (A^2 H1) W2 + b2)
  dim3 gd(625, 2);
  k_dense64<<<gd, 256, 0, stream>>>(H1, W2, b2, OUT2, 0);
  k_spmm1024<<<N_NODES, 256, 0, stream>>>(H1, ZB, rowp, csrs, csrv);
  k_dense64<<<gd, 256, 0, stream>>>(ZB, W2 + 4096, b2, OUT2, 1);
  k_spmm1024<<<N_NODES, 256, 0, stream>>>(ZB, H1, rowp, csrs, csrv);   // A^2 H1 -> H1 buffer
  k_dense64<<<gd, 256, 0, stream>>>(H1, W2 + 8192, b2, OUT2, 2);

  // GRU over T=8 (h0 = 0), gates buffer reuses ZB
  hipMemsetAsync(ha, 0, (size_t)BN*64*sizeof(float), stream);
  float* hcur = ha; float* hnxt = hb;
  dim3 gg(79, 16);
  for (int t = 0; t < 8; ++t) {
    k_gates<<<gg, 256, 0, stream>>>(OUT2, hcur, Wih, Whh, bih, bhh, ZB, t);
    k_gru_pt<<<5000, 256, 0, stream>>>(ZB, hcur, hnxt);
    float* tmp = hcur; hcur = hnxt; hnxt = tmp;
  }
  k_head<<<5000, 256, 0, stream>>>(hcur, Whead, bhead, y);
}

// Round 2
// 757.968 us; speedup vs baseline: 1.2170x; 1.2170x over previous
//
#include <hip/hip_runtime.h>
#include <math.h>

#define N_NODES 10000
#define B_SZ 2
#define T_STEPS 8
#define M_COLS 16
#define BN 20000
#define NM 160000

typedef __attribute__((ext_vector_type(8))) short short8;
typedef __attribute__((ext_vector_type(4))) float f32x4;

__device__ __forceinline__ float b2f(unsigned short u) {
  union { unsigned int i; float f; } x; x.i = ((unsigned int)u) << 16; return x.f;
}
__device__ __forceinline__ unsigned short f2b(float f) {
  unsigned int x = __float_as_uint(f);
  return (unsigned short)((x + 0x7fffu + ((x >> 16) & 1u)) >> 16);
}

// ---------------- CSR build ----------------
__global__ __launch_bounds__(256) void k_count(const int* __restrict__ dst, int* __restrict__ cnt, int E) {
  int e = blockIdx.x*256 + threadIdx.x;
  if (e < E) atomicAdd(&cnt[dst[e]], 1);
}

// single-block chunked exclusive scan of cnt[0..n) -> rowp[0..n]
__global__ __launch_bounds__(256) void k_scan(const int* __restrict__ cnt, int* __restrict__ rowp, int n) {
  const int K = 40;                       // 256*40 >= 10000
  int t = threadIdx.x;
  int beg = t*K;
  int end = beg + K < n ? beg + K : n;
  int s = 0;
  for (int i = beg; i < end; ++i) s += cnt[i];
  int lane = t & 63, w = t >> 6;
  int v = s;
#pragma unroll
  for (int off = 1; off < 64; off <<= 1) {
    int u = __shfl_up(v, off, 64);
    if (lane >= off) v += u;
  }
  __shared__ int wsum[4];
  if (lane == 63) wsum[w] = v;
  __syncthreads();
  int woff = 0;
  for (int i = 0; i < w; ++i) woff += wsum[i];
  int run = woff + v - s;                 // exclusive prefix of this chunk
  for (int i = beg; i < end; ++i) { rowp[i] = run; run += cnt[i]; }
  if (t == 255) rowp[n] = run;
}

__global__ __launch_bounds__(256) void k_fill(const int* __restrict__ src, const int* __restrict__ dst,
                                              const float* __restrict__ val, const int* __restrict__ rowp,
                                              int* __restrict__ cur, int* __restrict__ csrs,
                                              float* __restrict__ csrv, int E) {
  int e = blockIdx.x*256 + threadIdx.x;
  if (e >= E) return;
  int d = dst[e];
  int p = atomicAdd(&cur[d], 1);
  int slot = rowp[d] + p;
  csrs[slot] = src[e];
  csrv[slot] = val[e];
}

__global__ __launch_bounds__(256) void k_cvtw(const float* __restrict__ W, unsigned short* __restrict__ Wb, int n) {
  int i = blockIdx.x*256 + threadIdx.x;
  if (i < n) Wb[i] = f2b(W[i]);
}

// ---------------- layer 1 ----------------
__global__ __launch_bounds__(256) void k_x2h(const float* __restrict__ x, float* __restrict__ Z0) {
  int i = blockIdx.x*256 + threadIdx.x;
  if (i >= NM) return;
  int n = i >> 4, m = i & 15;
  int b = m >> 3, t = m & 7;
  Z0[i] = x[b*(N_NODES*T_STEPS) + n*T_STEPS + t];
}

__global__ __launch_bounds__(256) void k_spmm16(const float* __restrict__ Zin, float* __restrict__ Zout,
                                                const int* __restrict__ rowp, const int* __restrict__ csrs,
                                                const float* __restrict__ csrv) {
  int i = blockIdx.x*256 + threadIdx.x;
  if (i >= NM) return;
  int n = i >> 4, m = i & 15;
  int s = rowp[n], e = rowp[n+1];
  float acc = 0.f;
  for (int k = s; k < e; ++k)
    acc = fmaf(csrv[k], Zin[csrs[k]*16 + m], acc);
  Zout[i] = acc;
}

__global__ __launch_bounds__(256) void k_layer1(const float* __restrict__ Z0, const float* __restrict__ Z1,
                                                const float* __restrict__ Z2, const float* __restrict__ W1,
                                                const float* __restrict__ b1, unsigned short* __restrict__ H1b) {
  int i = blockIdx.x*256 + threadIdx.x;      // NM*64 threads
  int c = i & 63, nm = i >> 6;
  float v = fmaf(Z0[nm], W1[c], fmaf(Z1[nm], W1[64+c], fmaf(Z2[nm], W1[128+c], b1[c])));
  H1b[i] = f2b(v > 0.f ? v : 0.f);
}

// ---------------- layer 2 ----------------
// bf16 spmm over [N][1024] rows; 2 nodes per block, 128 lanes x 8 bf16 per node
__global__ __launch_bounds__(256) void k_spmmB(const unsigned short* __restrict__ Zin,
                                               unsigned short* __restrict__ Zout,
                                               const int* __restrict__ rowp, const int* __restrict__ csrs,
                                               const float* __restrict__ csrv) {
  int half = threadIdx.x >> 7;
  int lane = threadIdx.x & 127;
  int n = blockIdx.x*2 + half;
  int s = rowp[n], e = rowp[n+1];
  float acc[8] = {0,0,0,0,0,0,0,0};
  for (int k = s; k < e; ++k) {
    int src = csrs[k];
    float v = csrv[k];
    union { uint4 u; unsigned short s[8]; } z;
    z.u = *(const uint4*)(Zin + (size_t)src*1024 + lane*8);
#pragma unroll
    for (int j = 0; j < 8; ++j) acc[j] = fmaf(v, b2f(z.s[j]), acc[j]);
  }
  union { uint4 u; unsigned short s[8]; } o;
#pragma unroll
  for (int j = 0; j < 8; ++j) o.s[j] = f2b(acc[j]);
  *(uint4*)(Zout + (size_t)n*1024 + lane*8) = o.u;
}

// OUT2b[t][b][n][c] = relu(H1 W0 + Z1 W1 + Z2 W2 + b2), weights via scalar loads
__global__ __launch_bounds__(256) void k_layer2(const unsigned short* __restrict__ H1b,
                                                const unsigned short* __restrict__ Z1b,
                                                const unsigned short* __restrict__ Z2b,
                                                const float* __restrict__ W2,
                                                const float* __restrict__ b2,
                                                unsigned short* __restrict__ OUT2b) {
  int nm = blockIdx.x*256 + threadIdx.x;     // exactly NM
  const uint4* p0 = (const uint4*)(H1b + (size_t)nm*64);
  const uint4* p1 = (const uint4*)(Z1b + (size_t)nm*64);
  const uint4* p2 = (const uint4*)(Z2b + (size_t)nm*64);
  float acc[64];
#pragma unroll
  for (int c = 0; c < 64; ++c) acc[c] = b2[c];
#pragma unroll 1
  for (int kk = 0; kk < 8; ++kk) {
    union { uint4 v; unsigned short s[8]; } x0, x1, x2;
    x0.v = p0[kk]; x1.v = p1[kk]; x2.v = p2[kk];
    const float* wk0 = W2 + kk*8*64;
    const float* wk1 = W2 + 4096 + kk*8*64;
    const float* wk2 = W2 + 8192 + kk*8*64;
#pragma unroll
    for (int j = 0; j < 8; ++j) {
      float v0 = b2f(x0.s[j]), v1 = b2f(x1.s[j]), v2 = b2f(x2.s[j]);
#pragma unroll
      for (int c = 0; c < 64; ++c)
        acc[c] = fmaf(v0, wk0[j*64+c], fmaf(v1, wk1[j*64+c], fmaf(v2, wk2[j*64+c], acc[c])));
    }
  }
  int n = nm >> 4, m = nm & 15;
  int b = m >> 3, t = m & 7;
  unsigned short* dst = OUT2b + ((size_t)((t*2 + b)*N_NODES + n))*64;
  union { uint4 v; unsigned short s[8]; } o;
#pragma unroll
  for (int g = 0; g < 8; ++g) {
#pragma unroll
    for (int j = 0; j < 8; ++j) {
      float v = acc[g*8+j];
      o.s[j] = f2b(v > 0.f ? v : 0.f);
    }
    ((uint4*)dst)[g] = o.v;
  }
}

// ---------------- GRU ----------------
// GX[t*BN+bn][0:192] = x @ W_ih^T + b_ih, bf16 MFMA. One wave = 16 rows x 192 cols.
__global__ __launch_bounds__(256) void k_gx(const unsigned short* __restrict__ A,   // [160000][64] bf16
                                            const unsigned short* __restrict__ Bw,  // Wih bf16 [192*64]
                                            const float* __restrict__ bih,
                                            unsigned short* __restrict__ GX) {
  int wid = blockIdx.x*4 + (threadIdx.x >> 6);   // 0..9999
  int lane = threadIdx.x & 63;
  int lr = lane & 15, hi = lane >> 4;
  int rowbase = wid*16;
  const short* Ap = (const short*)A;
  const short* Bp = (const short*)Bw;
  short8 a0 = *(const short8*)(Ap + (size_t)(rowbase + lr)*64 + hi*8);
  short8 a1 = *(const short8*)(Ap + (size_t)(rowbase + lr)*64 + 32 + hi*8);
  f32x4 acc[12];
#pragma unroll
  for (int ct = 0; ct < 12; ++ct) {
    int col = ct*16 + lr;
    short8 b0 = *(const short8*)(Bp + col*64 + hi*8);
    short8 b1 = *(const short8*)(Bp + col*64 + 32 + hi*8);
    f32x4 c = {0.f, 0.f, 0.f, 0.f};
    c = __builtin_amdgcn_mfma_f32_16x16x32_bf16(a0, b0, c, 0, 0, 0);
    c = __builtin_amdgcn_mfma_f32_16x16x32_bf16(a1, b1, c, 0, 0, 0);
    acc[ct] = c;
  }
#pragma unroll
  for (int ct = 0; ct < 12; ++ct) {
    int col = ct*16 + lr;
    float bb = bih[col];
#pragma unroll
    for (int r = 0; r < 4; ++r) {
      int grow = rowbase + hi*4 + r;
      GX[(size_t)grow*192 + col] = f2b(acc[ct][r] + bb);
    }
  }
}

// one GRU step, fused gh-GEMV + pointwise. 64 rows/block; wave w handles gate cols [16w,16w+16)
__global__ __launch_bounds__(256) void k_step(const unsigned short* __restrict__ GX,
                                              const float* __restrict__ hprev,
                                              const float* __restrict__ Whh,
                                              const float* __restrict__ bhh,
                                              float* __restrict__ hnext, int tstep) {
  int tid = threadIdx.x;
  int row = blockIdx.x*64 + (tid & 63);
  int q = __builtin_amdgcn_readfirstlane(tid >> 6);   // wave-uniform -> SGPR
  bool act = row < BN;
  int rr = act ? row : 0;
  float h[64];
  const float4* hp = (const float4*)(hprev + (size_t)rr*64);
#pragma unroll
  for (int i = 0; i < 16; ++i) {
    float4 v = hp[i];
    h[4*i] = v.x; h[4*i+1] = v.y; h[4*i+2] = v.z; h[4*i+3] = v.w;
  }
  float ar[16], az[16], an[16];
#pragma unroll
  for (int u = 0; u < 16; ++u) {
    ar[u] = bhh[q*16 + u];
    az[u] = bhh[64 + q*16 + u];
    an[u] = bhh[128 + q*16 + u];
  }
#pragma unroll
  for (int u = 0; u < 16; ++u) {
    const float* w0 = Whh + (q*16 + u)*64;
    const float* w1 = Whh + (64 + q*16 + u)*64;
    const float* w2 = Whh + (128 + q*16 + u)*64;
    float a0 = ar[u], a1 = az[u], a2 = an[u];
#pragma unroll
    for (int j = 0; j < 64; ++j) {
      a0 = fmaf(h[j], w0[j], a0);
      a1 = fmaf(h[j], w1[j], a1);
      a2 = fmaf(h[j], w2[j], a2);
    }
    ar[u] = a0; az[u] = a1; an[u] = a2;
  }
  const unsigned short* gxrow = GX + ((size_t)tstep*BN + rr)*192;
  union U8 { uint4 v; unsigned short s[8]; };
  U8 R0, R1, Zg0, Zg1, Ng0, Ng1;
  R0.v  = *(const uint4*)(gxrow + q*16);
  R1.v  = *(const uint4*)(gxrow + q*16 + 8);
  Zg0.v = *(const uint4*)(gxrow + 64 + q*16);
  Zg1.v = *(const uint4*)(gxrow + 64 + q*16 + 8);
  Ng0.v = *(const uint4*)(gxrow + 128 + q*16);
  Ng1.v = *(const uint4*)(gxrow + 128 + q*16 + 8);
  float ho[16];
  const float4* hop = (const float4*)(hprev + (size_t)rr*64 + q*16);
#pragma unroll
  for (int i = 0; i < 4; ++i) {
    float4 v = hop[i];
    ho[4*i] = v.x; ho[4*i+1] = v.y; ho[4*i+2] = v.z; ho[4*i+3] = v.w;
  }
  float out[16];
#pragma unroll
  for (int u = 0; u < 16; ++u) {
    float gr = b2f(u < 8 ? R0.s[u]  : R1.s[u-8]);
    float gz = b2f(u < 8 ? Zg0.s[u] : Zg1.s[u-8]);
    float gn = b2f(u < 8 ? Ng0.s[u] : Ng1.s[u-8]);
    float r = 1.f/(1.f + __expf(-(gr + ar[u])));
    float z = 1.f/(1.f + __expf(-(gz + az[u])));
    float nn = tanhf(gn + r*an[u]);
    out[u] = (1.f - z)*nn + z*ho[u];
  }
  if (act) {
    float4* op = (float4*)(hnext + (size_t)row*64 + q*16);
#pragma unroll
    for (int i = 0; i < 4; ++i)
      op[i] = make_float4(out[4*i], out[4*i+1], out[4*i+2], out[4*i+3]);
  }
}

__global__ __launch_bounds__(256) void k_head(const float* __restrict__ h, const float* __restrict__ Wh,
                                              const float* __restrict__ bh, float* __restrict__ y) {
  int w = threadIdx.x >> 6, l = threadIdx.x & 63;
  int row = blockIdx.x*4 + w;                 // 5000*4 = BN
  float v = h[(size_t)row*64 + l] * Wh[l];
#pragma unroll
  for (int off = 32; off > 0; off >>= 1)
    v += __shfl_xor(v, off, 64);
  if (l == 0) y[row] = v + bh[0];
}

extern "C" void kernel_launch(void* const* d_in, const int* in_sizes, int n_in,
                              void* d_out, int out_size, void* d_ws, size_t ws_size,
                              hipStream_t stream) {
  const float* x    = (const float*)d_in[0];
  const int*   esrc = (const int*)d_in[1];
  const int*   edst = (const int*)d_in[2];
  const float* eval = (const float*)d_in[3];
  const float* W1   = (const float*)d_in[4];
  const float* b1   = (const float*)d_in[5];
  const float* W2   = (const float*)d_in[6];
  const float* b2   = (const float*)d_in[7];
  const float* Wih  = (const float*)d_in[8];
  const float* Whh  = (const float*)d_in[9];
  const float* bih  = (const float*)d_in[10];
  const float* bhh  = (const float*)d_in[11];
  const float* Whead= (const float*)d_in[12];
  const float* bhead= (const float*)d_in[13];
  int E = in_sizes[1];
  float* y = (float*)d_out;

  char* wsb = (char*)d_ws;
  // GX (61.44 MB) aliases H1b+ZB1+ZB2 (dead once k_layer2 finishes)
  unsigned short* H1b   = (unsigned short*)(wsb + 0);
  unsigned short* GX    = (unsigned short*)(wsb + 0);
  unsigned short* ZB1   = (unsigned short*)(wsb + 20480000);
  unsigned short* ZB2   = (unsigned short*)(wsb + 40960000);
  unsigned short* OUT2b = (unsigned short*)(wsb + 61440000);
  float* Z0   = (float*)(wsb + 81920000);
  float* Z1   = (float*)(wsb + 82560000);
  float* Z2   = (float*)(wsb + 83200000);
  float* ha   = (float*)(wsb + 83840000);
  float* hb   = (float*)(wsb + 88960000);
  int*   rowp = (int*)(wsb + 94080000);
  int*   cnt  = (int*)(wsb + 94120016);
  int*   csrs = (int*)(wsb + 94160032);
  float* csrv = (float*)(wsb + 94800032);
  unsigned short* Wbih = (unsigned short*)(wsb + 95440032);

  int eb = (E + 255) / 256;

  hipMemsetAsync(cnt, 0, N_NODES*sizeof(int), stream);
  k_count<<<eb, 256, 0, stream>>>(edst, cnt, E);
  k_scan<<<1, 256, 0, stream>>>(cnt, rowp, N_NODES);
  hipMemsetAsync(cnt, 0, N_NODES*sizeof(int), stream);
  k_fill<<<eb, 256, 0, stream>>>(esrc, edst, eval, rowp, cnt, csrs, csrv, E);
  k_cvtw<<<48, 256, 0, stream>>>(Wih, Wbih, 192*64);

  k_x2h<<<625, 256, 0, stream>>>(x, Z0);
  k_spmm16<<<625, 256, 0, stream>>>(Z0, Z1, rowp, csrs, csrv);
  k_spmm16<<<625, 256, 0, stream>>>(Z1, Z2, rowp, csrs, csrv);
  k_layer1<<<40000, 256, 0, stream>>>(Z0, Z1, Z2, W1, b1, H1b);

  k_spmmB<<<5000, 256, 0, stream>>>(H1b, ZB1, rowp, csrs, csrv);
  k_spmmB<<<5000, 256, 0, stream>>>(ZB1, ZB2, rowp, csrs, csrv);
  k_layer2<<<625, 256, 0, stream>>>(H1b, ZB1, ZB2, W2, b2, OUT2b);

  k_gx<<<2500, 256, 0, stream>>>(OUT2b, Wbih, bih, GX);

  hipMemsetAsync(ha, 0, (size_t)BN*64*sizeof(float), stream);
  float* hc = ha; float* hn = hb;
  for (int t = 0; t < 8; ++t) {
    k_step<<<313, 256, 0, stream>>>(GX, hc, Whh, bhh, hn, t);
    float* tmp = hc; hc = hn; hn = tmp;
  }
  k_head<<<5000, 256, 0, stream>>>(hc, Whead, bhead, y);
}

// Round 3
// 655.109 us; speedup vs baseline: 1.4080x; 1.1570x over previous
//
#include <hip/hip_runtime.h>
#include <math.h>

#define N_NODES 10000
#define B_SZ 2
#define T_STEPS 8
#define M_COLS 16
#define BN 20000
#define NM 160000

typedef __attribute__((ext_vector_type(8))) short short8;
typedef __attribute__((ext_vector_type(4))) float f32x4;

__device__ __forceinline__ float b2f(unsigned short u) {
  union { unsigned int i; float f; } x; x.i = ((unsigned int)u) << 16; return x.f;
}
__device__ __forceinline__ unsigned short f2b(float f) {
  unsigned int x = __float_as_uint(f);
  return (unsigned short)((x + 0x7fffu + ((x >> 16) & 1u)) >> 16);
}

// ---------------- CSR build ----------------
__global__ __launch_bounds__(256) void k_count(const int* __restrict__ dst, int* __restrict__ cnt, int E) {
  int e = blockIdx.x*256 + threadIdx.x;
  if (e < E) atomicAdd(&cnt[dst[e]], 1);
}

__global__ __launch_bounds__(256) void k_scan(const int* __restrict__ cnt, int* __restrict__ rowp, int n) {
  const int K = 40;
  int t = threadIdx.x;
  int beg = t*K;
  int end = beg + K < n ? beg + K : n;
  int s = 0;
  for (int i = beg; i < end; ++i) s += cnt[i];
  int lane = t & 63, w = t >> 6;
  int v = s;
#pragma unroll
  for (int off = 1; off < 64; off <<= 1) {
    int u = __shfl_up(v, off, 64);
    if (lane >= off) v += u;
  }
  __shared__ int wsum[4];
  if (lane == 63) wsum[w] = v;
  __syncthreads();
  int woff = 0;
  for (int i = 0; i < w; ++i) woff += wsum[i];
  int run = woff + v - s;
  for (int i = beg; i < end; ++i) { rowp[i] = run; run += cnt[i]; }
  if (t == 255) rowp[n] = run;
}

__global__ __launch_bounds__(256) void k_fill(const int* __restrict__ src, const int* __restrict__ dst,
                                              const float* __restrict__ val, const int* __restrict__ rowp,
                                              int* __restrict__ cur, int* __restrict__ csrs,
                                              float* __restrict__ csrv, int E) {
  int e = blockIdx.x*256 + threadIdx.x;
  if (e >= E) return;
  int d = dst[e];
  int p = atomicAdd(&cur[d], 1);
  int slot = rowp[d] + p;
  csrs[slot] = src[e];
  csrv[slot] = val[e];
}

__global__ __launch_bounds__(256) void k_cvtw(const float* __restrict__ W, unsigned short* __restrict__ Wb, int n) {
  int i = blockIdx.x*256 + threadIdx.x;
  if (i < n) Wb[i] = f2b(W[i]);
}

// Wt[p][c][k] = W2[p][k][c]  (bf16)
__global__ __launch_bounds__(256) void k_cvtw2(const float* __restrict__ W2, unsigned short* __restrict__ Wt) {
  int i = blockIdx.x*256 + threadIdx.x;
  if (i >= 3*64*64) return;
  int p = i >> 12, rem = i & 4095, c = rem >> 6, k = rem & 63;
  Wt[i] = f2b(W2[p*4096 + k*64 + c]);
}

// ---------------- layer 1 ----------------
__global__ __launch_bounds__(256) void k_x2h(const float* __restrict__ x, float* __restrict__ Z0) {
  int i = blockIdx.x*256 + threadIdx.x;
  if (i >= NM) return;
  int n = i >> 4, m = i & 15;
  int b = m >> 3, t = m & 7;
  Z0[i] = x[b*(N_NODES*T_STEPS) + n*T_STEPS + t];
}

__global__ __launch_bounds__(256) void k_spmm16(const float* __restrict__ Zin, float* __restrict__ Zout,
                                                const int* __restrict__ rowp, const int* __restrict__ csrs,
                                                const float* __restrict__ csrv) {
  int i = blockIdx.x*256 + threadIdx.x;
  if (i >= NM) return;
  int n = i >> 4, m = i & 15;
  int s = rowp[n], e = rowp[n+1];
  float acc = 0.f;
  for (int k = s; k < e; ++k)
    acc = fmaf(csrv[k], Zin[csrs[k]*16 + m], acc);
  Zout[i] = acc;
}

__global__ __launch_bounds__(256) void k_layer1(const float* __restrict__ Z0, const float* __restrict__ Z1,
                                                const float* __restrict__ Z2, const float* __restrict__ W1,
                                                const float* __restrict__ b1, unsigned short* __restrict__ H1b) {
  int i = blockIdx.x*256 + threadIdx.x;
  int c = i & 63, nm = i >> 6;
  float v = fmaf(Z0[nm], W1[c], fmaf(Z1[nm], W1[64+c], fmaf(Z2[nm], W1[128+c], b1[c])));
  H1b[i] = f2b(v > 0.f ? v : 0.f);
}

// ---------------- layer 2 ----------------
// chunked bf16 spmm: 8 chunks x 128 feats; chunk slab = 2.56 MB (fits per-XCD L2)
__global__ __launch_bounds__(256) void k_spmmC(const unsigned short* __restrict__ Zin,
                                               unsigned short* __restrict__ Zout,
                                               const int* __restrict__ rowp, const int* __restrict__ csrs,
                                               const float* __restrict__ csrv) {
  int c = blockIdx.x / 625;                       // chunk-major dispatch
  int n = (blockIdx.x % 625)*16 + (threadIdx.x >> 4);
  int l = threadIdx.x & 15;
  int off = c*128 + l*8;
  int s = rowp[n], e = rowp[n+1];
  float acc[8] = {0,0,0,0,0,0,0,0};
  for (int k = s; k < e; ++k) {
    int src = csrs[k];
    float v = csrv[k];
    union { uint4 u; unsigned short s[8]; } z;
    z.u = *(const uint4*)(Zin + (size_t)src*1024 + off);
#pragma unroll
    for (int j = 0; j < 8; ++j) acc[j] = fmaf(v, b2f(z.s[j]), acc[j]);
  }
  union { uint4 u; unsigned short s[8]; } o;
#pragma unroll
  for (int j = 0; j < 8; ++j) o.s[j] = f2b(acc[j]);
  *(uint4*)(Zout + (size_t)n*1024 + off) = o.u;
}

// MFMA layer 2: out[nm][c] = relu(sum_p Zp[nm][:] @ W2[p] + b2), K=192 via 3x64
__global__ __launch_bounds__(256) void k_layer2m(const unsigned short* __restrict__ H1b,
                                                 const unsigned short* __restrict__ Z1b,
                                                 const unsigned short* __restrict__ Z2b,
                                                 const unsigned short* __restrict__ Wt,
                                                 const float* __restrict__ b2,
                                                 unsigned short* __restrict__ OUT2b) {
  int wid = blockIdx.x*4 + (threadIdx.x >> 6);    // 0..9999
  int lane = threadIdx.x & 63;
  int lr = lane & 15, hi = lane >> 4;
  int rowbase = wid*16;
  const short* A0 = (const short*)H1b + (size_t)(rowbase + lr)*64;
  const short* A1 = (const short*)Z1b + (size_t)(rowbase + lr)*64;
  const short* A2 = (const short*)Z2b + (size_t)(rowbase + lr)*64;
  short8 a[3][2];
  a[0][0] = *(const short8*)(A0 + hi*8); a[0][1] = *(const short8*)(A0 + 32 + hi*8);
  a[1][0] = *(const short8*)(A1 + hi*8); a[1][1] = *(const short8*)(A1 + 32 + hi*8);
  a[2][0] = *(const short8*)(A2 + hi*8); a[2][1] = *(const short8*)(A2 + 32 + hi*8);
  const short* Bp = (const short*)Wt;
  f32x4 acc[4];
#pragma unroll
  for (int ct = 0; ct < 4; ++ct) {
    int col = ct*16 + lr;
    f32x4 c = {0.f, 0.f, 0.f, 0.f};
#pragma unroll
    for (int p = 0; p < 3; ++p) {
      short8 b0 = *(const short8*)(Bp + p*4096 + col*64 + hi*8);
      short8 b1 = *(const short8*)(Bp + p*4096 + col*64 + 32 + hi*8);
      c = __builtin_amdgcn_mfma_f32_16x16x32_bf16(a[p][0], b0, c, 0, 0, 0);
      c = __builtin_amdgcn_mfma_f32_16x16x32_bf16(a[p][1], b1, c, 0, 0, 0);
    }
    acc[ct] = c;
  }
#pragma unroll
  for (int ct = 0; ct < 4; ++ct) {
    int col = ct*16 + lr;
    float bb = b2[col];
#pragma unroll
    for (int r = 0; r < 4; ++r) {
      int nm = rowbase + hi*4 + r;
      int n = nm >> 4, m = nm & 15;
      int bi = m >> 3, t = m & 7;
      float v = acc[ct][r] + bb;
      OUT2b[((size_t)((t*2 + bi)*N_NODES + n))*64 + col] = f2b(v > 0.f ? v : 0.f);
    }
  }
}

// ---------------- GRU ----------------
// GX[t*BN+bn][0:192] = x @ W_ih^T + b_ih (bf16 MFMA)
__global__ __launch_bounds__(256) void k_gx(const unsigned short* __restrict__ A,
                                            const unsigned short* __restrict__ Bw,
                                            const float* __restrict__ bih,
                                            unsigned short* __restrict__ GX) {
  int wid = blockIdx.x*4 + (threadIdx.x >> 6);
  int lane = threadIdx.x & 63;
  int lr = lane & 15, hi = lane >> 4;
  int rowbase = wid*16;
  const short* Ap = (const short*)A;
  const short* Bp = (const short*)Bw;
  short8 a0 = *(const short8*)(Ap + (size_t)(rowbase + lr)*64 + hi*8);
  short8 a1 = *(const short8*)(Ap + (size_t)(rowbase + lr)*64 + 32 + hi*8);
  f32x4 acc[12];
#pragma unroll
  for (int ct = 0; ct < 12; ++ct) {
    int col = ct*16 + lr;
    short8 b0 = *(const short8*)(Bp + col*64 + hi*8);
    short8 b1 = *(const short8*)(Bp + col*64 + 32 + hi*8);
    f32x4 c = {0.f, 0.f, 0.f, 0.f};
    c = __builtin_amdgcn_mfma_f32_16x16x32_bf16(a0, b0, c, 0, 0, 0);
    c = __builtin_amdgcn_mfma_f32_16x16x32_bf16(a1, b1, c, 0, 0, 0);
    acc[ct] = c;
  }
#pragma unroll
  for (int ct = 0; ct < 12; ++ct) {
    int col = ct*16 + lr;
    float bb = bih[col];
#pragma unroll
    for (int r = 0; r < 4; ++r) {
      int grow = rowbase + hi*4 + r;
      GX[(size_t)grow*192 + col] = f2b(acc[ct][r] + bb);
    }
  }
}

// fused 8-step GRU + head. 64 rows/block, 8 waves; wave q owns gate cols [8q,8q+8).
// h kept fp32 in LDS (transposed [col][row]) — no recurrent rounding.
__global__ __launch_bounds__(512) void k_gru(const unsigned short* __restrict__ GX,
                                             const float* __restrict__ Whh,
                                             const float* __restrict__ bhh,
                                             const float* __restrict__ Whead,
                                             const float* __restrict__ bhead,
                                             float* __restrict__ y) {
  __shared__ float hs[64][64];          // [col][row]
  int tid = threadIdx.x;
  int lane = tid & 63;
  int q = __builtin_amdgcn_readfirstlane(tid >> 6);   // 0..7, wave-uniform
  int row = blockIdx.x*64 + lane;
  bool act = row < BN;
  int rr = act ? row : BN - 1;
  for (int i = tid; i < 64*64; i += 512) ((float*)hs)[i] = 0.f;
  float br[8], bz[8], bnn[8];
#pragma unroll
  for (int u = 0; u < 8; ++u) {
    br[u]  = bhh[q*8 + u];
    bz[u]  = bhh[64 + q*8 + u];
    bnn[u] = bhh[128 + q*8 + u];
  }
  __syncthreads();
#pragma unroll 1
  for (int t = 0; t < 8; ++t) {
    float h[64];
#pragma unroll
    for (int j = 0; j < 64; ++j) h[j] = hs[j][lane];
    float ar[8], az[8], an[8];
#pragma unroll
    for (int u = 0; u < 8; ++u) {
      const float* w0 = Whh + (q*8 + u)*64;
      const float* w1 = Whh + (64 + q*8 + u)*64;
      const float* w2 = Whh + (128 + q*8 + u)*64;
      float a0 = br[u], a1 = bz[u], a2 = bnn[u];
#pragma unroll
      for (int j = 0; j < 64; ++j) {
        a0 = fmaf(h[j], w0[j], a0);
        a1 = fmaf(h[j], w1[j], a1);
        a2 = fmaf(h[j], w2[j], a2);
      }
      ar[u] = a0; az[u] = a1; an[u] = a2;
    }
    const unsigned short* gxrow = GX + ((size_t)t*BN + rr)*192;
    union { uint4 v; unsigned short s[8]; } Rx, Zx, Nx;
    Rx.v = *(const uint4*)(gxrow + q*8);
    Zx.v = *(const uint4*)(gxrow + 64 + q*8);
    Nx.v = *(const uint4*)(gxrow + 128 + q*8);
    __syncthreads();                      // all reads of hs done
    float out[8];
#pragma unroll
    for (int u = 0; u < 8; ++u) {
      float r = 1.f/(1.f + __expf(-(b2f(Rx.s[u]) + ar[u])));
      float z = 1.f/(1.f + __expf(-(b2f(Zx.s[u]) + az[u])));
      float nn = tanhf(b2f(Nx.s[u]) + r*an[u]);
      out[u] = (1.f - z)*nn + z*h[q*8 + u];
    }
#pragma unroll
    for (int u = 0; u < 8; ++u) hs[q*8 + u][lane] = out[u];
    __syncthreads();
  }
  float acc = 0.f;
#pragma unroll
  for (int j = 0; j < 64; ++j) acc = fmaf(hs[j][lane], Whead[j], acc);
  if (act && q == 0) y[row] = acc + bhead[0];
}

extern "C" void kernel_launch(void* const* d_in, const int* in_sizes, int n_in,
                              void* d_out, int out_size, void* d_ws, size_t ws_size,
                              hipStream_t stream) {
  const float* x    = (const float*)d_in[0];
  const int*   esrc = (const int*)d_in[1];
  const int*   edst = (const int*)d_in[2];
  const float* eval = (const float*)d_in[3];
  const float* W1   = (const float*)d_in[4];
  const float* b1   = (const float*)d_in[5];
  const float* W2   = (const float*)d_in[6];
  const float* b2   = (const float*)d_in[7];
  const float* Wih  = (const float*)d_in[8];
  const float* Whh  = (const float*)d_in[9];
  const float* bih  = (const float*)d_in[10];
  const float* bhh  = (const float*)d_in[11];
  const float* Whead= (const float*)d_in[12];
  const float* bhead= (const float*)d_in[13];
  int E = in_sizes[1];
  float* y = (float*)d_out;

  char* wsb = (char*)d_ws;
  unsigned short* H1b   = (unsigned short*)(wsb + 0);
  unsigned short* GX    = (unsigned short*)(wsb + 0);          // aliases H1b/ZB1/ZB2
  unsigned short* ZB1   = (unsigned short*)(wsb + 20480000);
  unsigned short* ZB2   = (unsigned short*)(wsb + 40960000);
  unsigned short* OUT2b = (unsigned short*)(wsb + 61440000);
  float* Z0   = (float*)(wsb + 81920000);
  float* Z1   = (float*)(wsb + 82560000);
  float* Z2   = (float*)(wsb + 83200000);
  int*   rowp = (int*)(wsb + 83840000);
  int*   cnt  = (int*)(wsb + 83880004);
  int*   csrs = (int*)(wsb + 83920004);
  float* csrv = (float*)(wsb + 84560004);
  unsigned short* Wbih = (unsigned short*)(wsb + 85200004);
  unsigned short* W2t  = (unsigned short*)(wsb + 85224580);

  int eb = (E + 255) / 256;

  hipMemsetAsync(cnt, 0, N_NODES*sizeof(int), stream);
  k_count<<<eb, 256, 0, stream>>>(edst, cnt, E);
  k_scan<<<1, 256, 0, stream>>>(cnt, rowp, N_NODES);
  hipMemsetAsync(cnt, 0, N_NODES*sizeof(int), stream);
  k_fill<<<eb, 256, 0, stream>>>(esrc, edst, eval, rowp, cnt, csrs, csrv, E);
  k_cvtw<<<48, 256, 0, stream>>>(Wih, Wbih, 192*64);
  k_cvtw2<<<48, 256, 0, stream>>>(W2, W2t);

  k_x2h<<<625, 256, 0, stream>>>(x, Z0);
  k_spmm16<<<625, 256, 0, stream>>>(Z0, Z1, rowp, csrs, csrv);
  k_spmm16<<<625, 256, 0, stream>>>(Z1, Z2, rowp, csrs, csrv);
  k_layer1<<<40000, 256, 0, stream>>>(Z0, Z1, Z2, W1, b1, H1b);

  k_spmmC<<<5000, 256, 0, stream>>>(H1b, ZB1, rowp, csrs, csrv);
  k_spmmC<<<5000, 256, 0, stream>>>(ZB1, ZB2, rowp, csrs, csrv);
  k_layer2m<<<2500, 256, 0, stream>>>(H1b, ZB1, ZB2, W2t, b2, OUT2b);

  k_gx<<<2500, 256, 0, stream>>>(OUT2b, Wbih, bih, GX);
  k_gru<<<313, 512, 0, stream>>>(GX, Whh, bhh, Whead, bhead, y);
}

// Round 4
// 583.360 us; speedup vs baseline: 1.5812x; 1.1230x over previous
//
#include <hip/hip_runtime.h>
#include <math.h>

#define N_NODES 10000
#define B_SZ 2
#define T_STEPS 8
#define M_COLS 16
#define BN 20000
#define NM 160000

typedef __attribute__((ext_vector_type(8))) short short8;
typedef __attribute__((ext_vector_type(4))) float f32x4;

__device__ __forceinline__ float b2f(unsigned short u) {
  union { unsigned int i; float f; } x; x.i = ((unsigned int)u) << 16; return x.f;
}
__device__ __forceinline__ unsigned short f2b(float f) {
  unsigned int x = __float_as_uint(f);
  return (unsigned short)((x + 0x7fffu + ((x >> 16) & 1u)) >> 16);
}

// ---------------- CSR build ----------------
__global__ __launch_bounds__(256) void k_count(const int* __restrict__ dst, int* __restrict__ cnt, int E) {
  int e = blockIdx.x*256 + threadIdx.x;
  if (e < E) atomicAdd(&cnt[dst[e]], 1);
}

__global__ __launch_bounds__(256) void k_scan(const int* __restrict__ cnt, int* __restrict__ rowp, int n) {
  const int K = 40;
  int t = threadIdx.x;
  int beg = t*K;
  int end = beg + K < n ? beg + K : n;
  int s = 0;
  for (int i = beg; i < end; ++i) s += cnt[i];
  int lane = t & 63, w = t >> 6;
  int v = s;
#pragma unroll
  for (int off = 1; off < 64; off <<= 1) {
    int u = __shfl_up(v, off, 64);
    if (lane >= off) v += u;
  }
  __shared__ int wsum[4];
  if (lane == 63) wsum[w] = v;
  __syncthreads();
  int woff = 0;
  for (int i = 0; i < w; ++i) woff += wsum[i];
  int run = woff + v - s;
  for (int i = beg; i < end; ++i) { rowp[i] = run; run += cnt[i]; }
  if (t == 255) rowp[n] = run;
}

__global__ __launch_bounds__(256) void k_fill(const int* __restrict__ src, const int* __restrict__ dst,
                                              const float* __restrict__ val, const int* __restrict__ rowp,
                                              int* __restrict__ cur, int* __restrict__ csrs,
                                              float* __restrict__ csrv, int E) {
  int e = blockIdx.x*256 + threadIdx.x;
  if (e >= E) return;
  int d = dst[e];
  int p = atomicAdd(&cur[d], 1);
  int slot = rowp[d] + p;
  csrs[slot] = src[e];
  csrv[slot] = val[e];
}

__global__ __launch_bounds__(256) void k_cvtw(const float* __restrict__ W, unsigned short* __restrict__ Wb, int n) {
  int i = blockIdx.x*256 + threadIdx.x;
  if (i < n) Wb[i] = f2b(W[i]);
}

// Wt[p][c][k] = W2[p][k][c]  (bf16)
__global__ __launch_bounds__(256) void k_cvtw2(const float* __restrict__ W2, unsigned short* __restrict__ Wt) {
  int i = blockIdx.x*256 + threadIdx.x;
  if (i >= 3*64*64) return;
  int p = i >> 12, rem = i & 4095, c = rem >> 6, k = rem & 63;
  Wt[i] = f2b(W2[p*4096 + k*64 + c]);
}

// ---------------- layer 1 ----------------
__global__ __launch_bounds__(256) void k_x2h(const float* __restrict__ x, float* __restrict__ Z0) {
  int i = blockIdx.x*256 + threadIdx.x;
  if (i >= NM) return;
  int n = i >> 4, m = i & 15;
  int b = m >> 3, t = m & 7;
  Z0[i] = x[b*(N_NODES*T_STEPS) + n*T_STEPS + t];
}

__global__ __launch_bounds__(256) void k_spmm16(const float* __restrict__ Zin, float* __restrict__ Zout,
                                                const int* __restrict__ rowp, const int* __restrict__ csrs,
                                                const float* __restrict__ csrv) {
  int i = blockIdx.x*256 + threadIdx.x;
  if (i >= NM) return;
  int n = i >> 4, m = i & 15;
  int s = rowp[n], e = rowp[n+1];
  float acc = 0.f;
  for (int k = s; k < e; ++k)
    acc = fmaf(csrv[k], Zin[csrs[k]*16 + m], acc);
  Zout[i] = acc;
}

__global__ __launch_bounds__(256) void k_layer1(const float* __restrict__ Z0, const float* __restrict__ Z1,
                                                const float* __restrict__ Z2, const float* __restrict__ W1,
                                                const float* __restrict__ b1, unsigned short* __restrict__ H1b) {
  int i = blockIdx.x*256 + threadIdx.x;
  int c = i & 63, nm = i >> 6;
  float v = fmaf(Z0[nm], W1[c], fmaf(Z1[nm], W1[64+c], fmaf(Z2[nm], W1[128+c], b1[c])));
  H1b[i] = f2b(v > 0.f ? v : 0.f);
}

// ---------------- layer 2 ----------------
// chunked bf16 spmm: 8 chunks x 128 feats; chunk slab = 2.56 MB (fits per-XCD L2)
__global__ __launch_bounds__(256) void k_spmmC(const unsigned short* __restrict__ Zin,
                                               unsigned short* __restrict__ Zout,
                                               const int* __restrict__ rowp, const int* __restrict__ csrs,
                                               const float* __restrict__ csrv) {
  int c = blockIdx.x / 625;                       // chunk-major dispatch
  int n = (blockIdx.x % 625)*16 + (threadIdx.x >> 4);
  int l = threadIdx.x & 15;
  int off = c*128 + l*8;
  int s = rowp[n], e = rowp[n+1];
  float acc[8] = {0,0,0,0,0,0,0,0};
  for (int k = s; k < e; ++k) {
    int src = csrs[k];
    float v = csrv[k];
    union { uint4 u; unsigned short s[8]; } z;
    z.u = *(const uint4*)(Zin + (size_t)src*1024 + off);
#pragma unroll
    for (int j = 0; j < 8; ++j) acc[j] = fmaf(v, b2f(z.s[j]), acc[j]);
  }
  union { uint4 u; unsigned short s[8]; } o;
#pragma unroll
  for (int j = 0; j < 8; ++j) o.s[j] = f2b(acc[j]);
  *(uint4*)(Zout + (size_t)n*1024 + off) = o.u;
}

// MFMA layer 2: out[nm][c] = relu(sum_p Zp[nm][:] @ W2[p] + b2), K=192 via 3x64
__global__ __launch_bounds__(256) void k_layer2m(const unsigned short* __restrict__ H1b,
                                                 const unsigned short* __restrict__ Z1b,
                                                 const unsigned short* __restrict__ Z2b,
                                                 const unsigned short* __restrict__ Wt,
                                                 const float* __restrict__ b2,
                                                 unsigned short* __restrict__ OUT2b) {
  int wid = blockIdx.x*4 + (threadIdx.x >> 6);    // 0..9999
  int lane = threadIdx.x & 63;
  int lr = lane & 15, hi = lane >> 4;
  int rowbase = wid*16;
  const short* A0 = (const short*)H1b + (size_t)(rowbase + lr)*64;
  const short* A1 = (const short*)Z1b + (size_t)(rowbase + lr)*64;
  const short* A2 = (const short*)Z2b + (size_t)(rowbase + lr)*64;
  short8 a[3][2];
  a[0][0] = *(const short8*)(A0 + hi*8); a[0][1] = *(const short8*)(A0 + 32 + hi*8);
  a[1][0] = *(const short8*)(A1 + hi*8); a[1][1] = *(const short8*)(A1 + 32 + hi*8);
  a[2][0] = *(const short8*)(A2 + hi*8); a[2][1] = *(const short8*)(A2 + 32 + hi*8);
  const short* Bp = (const short*)Wt;
  f32x4 acc[4];
#pragma unroll
  for (int ct = 0; ct < 4; ++ct) {
    int col = ct*16 + lr;
    f32x4 c = {0.f, 0.f, 0.f, 0.f};
#pragma unroll
    for (int p = 0; p < 3; ++p) {
      short8 b0 = *(const short8*)(Bp + p*4096 + col*64 + hi*8);
      short8 b1 = *(const short8*)(Bp + p*4096 + col*64 + 32 + hi*8);
      c = __builtin_amdgcn_mfma_f32_16x16x32_bf16(a[p][0], b0, c, 0, 0, 0);
      c = __builtin_amdgcn_mfma_f32_16x16x32_bf16(a[p][1], b1, c, 0, 0, 0);
    }
    acc[ct] = c;
  }
#pragma unroll
  for (int ct = 0; ct < 4; ++ct) {
    int col = ct*16 + lr;
    float bb = b2[col];
#pragma unroll
    for (int r = 0; r < 4; ++r) {
      int nm = rowbase + hi*4 + r;
      int n = nm >> 4, m = nm & 15;
      int bi = m >> 3, t = m & 7;
      float v = acc[ct][r] + bb;
      OUT2b[((size_t)((t*2 + bi)*N_NODES + n))*64 + col] = f2b(v > 0.f ? v : 0.f);
    }
  }
}

// ---------------- GRU ----------------
// GX[t*BN+bn][0:192] = x @ W_ih^T + b_ih (bf16 MFMA)
__global__ __launch_bounds__(256) void k_gx(const unsigned short* __restrict__ A,
                                            const unsigned short* __restrict__ Bw,
                                            const float* __restrict__ bih,
                                            unsigned short* __restrict__ GX) {
  int wid = blockIdx.x*4 + (threadIdx.x >> 6);
  int lane = threadIdx.x & 63;
  int lr = lane & 15, hi = lane >> 4;
  int rowbase = wid*16;
  const short* Ap = (const short*)A;
  const short* Bp = (const short*)Bw;
  short8 a0 = *(const short8*)(Ap + (size_t)(rowbase + lr)*64 + hi*8);
  short8 a1 = *(const short8*)(Ap + (size_t)(rowbase + lr)*64 + 32 + hi*8);
  f32x4 acc[12];
#pragma unroll
  for (int ct = 0; ct < 12; ++ct) {
    int col = ct*16 + lr;
    short8 b0 = *(const short8*)(Bp + col*64 + hi*8);
    short8 b1 = *(const short8*)(Bp + col*64 + 32 + hi*8);
    f32x4 c = {0.f, 0.f, 0.f, 0.f};
    c = __builtin_amdgcn_mfma_f32_16x16x32_bf16(a0, b0, c, 0, 0, 0);
    c = __builtin_amdgcn_mfma_f32_16x16x32_bf16(a1, b1, c, 0, 0, 0);
    acc[ct] = c;
  }
#pragma unroll
  for (int ct = 0; ct < 12; ++ct) {
    int col = ct*16 + lr;
    float bb = bih[col];
#pragma unroll
    for (int r = 0; r < 4; ++r) {
      int grow = rowbase + hi*4 + r;
      GX[(size_t)grow*192 + col] = f2b(acc[ct][r] + bb);
    }
  }
}

// fused 8-step GRU + head. 64 rows/block, 8 waves; wave q owns gate cols [8q,8q+8).
// h kept fp32 in LDS (transposed [col][row]); per-thread h[64] in VGPRs
// (ALL register-array indices compile-time constant — rule #20).
__global__ __launch_bounds__(512) void k_gru(const unsigned short* __restrict__ GX,
                                             const float* __restrict__ Whh,
                                             const float* __restrict__ bhh,
                                             const float* __restrict__ Whead,
                                             const float* __restrict__ bhead,
                                             float* __restrict__ y) {
  __shared__ float hs[64][64];          // [col][row]
  int tid = threadIdx.x;
  int lane = tid & 63;
  int q = __builtin_amdgcn_readfirstlane(tid >> 6);   // 0..7, wave-uniform
  int row = blockIdx.x*64 + lane;
  bool act = row < BN;
  int rr = act ? row : BN - 1;
  for (int i = tid; i < 64*64; i += 512) ((float*)hs)[i] = 0.f;
  float br[8], bz[8], bnn[8];
#pragma unroll
  for (int u = 0; u < 8; ++u) {
    br[u]  = bhh[q*8 + u];
    bz[u]  = bhh[64 + q*8 + u];
    bnn[u] = bhh[128 + q*8 + u];
  }
  __syncthreads();
#pragma unroll 1
  for (int t = 0; t < 8; ++t) {
    float h[64];
#pragma unroll
    for (int j = 0; j < 64; ++j) h[j] = hs[j][lane];
    float ar[8], az[8], an[8];
#pragma unroll
    for (int u = 0; u < 8; ++u) {
      const float* w0 = Whh + (q*8 + u)*64;
      const float* w1 = Whh + (64 + q*8 + u)*64;
      const float* w2 = Whh + (128 + q*8 + u)*64;
      float a0 = br[u], a1 = bz[u], a2 = bnn[u];
#pragma unroll
      for (int j = 0; j < 64; ++j) {
        a0 = fmaf(h[j], w0[j], a0);
        a1 = fmaf(h[j], w1[j], a1);
        a2 = fmaf(h[j], w2[j], a2);
      }
      ar[u] = a0; az[u] = a1; an[u] = a2;
    }
    const unsigned short* gxrow = GX + ((size_t)t*BN + rr)*192;
    union { uint4 v; unsigned short s[8]; } Rx, Zx, Nx;
    Rx.v = *(const uint4*)(gxrow + q*8);
    Zx.v = *(const uint4*)(gxrow + 64 + q*8);
    Nx.v = *(const uint4*)(gxrow + 128 + q*8);
    __syncthreads();                      // all reads of hs done
    float out[8];
#pragma unroll
    for (int u = 0; u < 8; ++u) {
      float hq = hs[q*8 + u][lane];       // LDS read (runtime q legal here);
                                          // same-thread addr, rewritten below
      float r = 1.f/(1.f + __expf(-(b2f(Rx.s[u]) + ar[u])));
      float z = 1.f/(1.f + __expf(-(b2f(Zx.s[u]) + az[u])));
      float nn = tanhf(b2f(Nx.s[u]) + r*an[u]);
      out[u] = (1.f - z)*nn + z*hq;
    }
#pragma unroll
    for (int u = 0; u < 8; ++u) hs[q*8 + u][lane] = out[u];
    __syncthreads();
  }
  float acc = 0.f;
#pragma unroll
  for (int j = 0; j < 64; ++j) acc = fmaf(hs[j][lane], Whead[j], acc);
  if (act && q == 0) y[row] = acc + bhead[0];
}

extern "C" void kernel_launch(void* const* d_in, const int* in_sizes, int n_in,
                              void* d_out, int out_size, void* d_ws, size_t ws_size,
                              hipStream_t stream) {
  const float* x    = (const float*)d_in[0];
  const int*   esrc = (const int*)d_in[1];
  const int*   edst = (const int*)d_in[2];
  const float* eval = (const float*)d_in[3];
  const float* W1   = (const float*)d_in[4];
  const float* b1   = (const float*)d_in[5];
  const float* W2   = (const float*)d_in[6];
  const float* b2   = (const float*)d_in[7];
  const float* Wih  = (const float*)d_in[8];
  const float* Whh  = (const float*)d_in[9];
  const float* bih  = (const float*)d_in[10];
  const float* bhh  = (const float*)d_in[11];
  const float* Whead= (const float*)d_in[12];
  const float* bhead= (const float*)d_in[13];
  int E = in_sizes[1];
  float* y = (float*)d_out;

  char* wsb = (char*)d_ws;
  unsigned short* H1b   = (unsigned short*)(wsb + 0);
  unsigned short* GX    = (unsigned short*)(wsb + 0);          // aliases H1b/ZB1/ZB2
  unsigned short* ZB1   = (unsigned short*)(wsb + 20480000);
  unsigned short* ZB2   = (unsigned short*)(wsb + 40960000);
  unsigned short* OUT2b = (unsigned short*)(wsb + 61440000);
  float* Z0   = (float*)(wsb + 81920000);
  float* Z1   = (float*)(wsb + 82560000);
  float* Z2   = (float*)(wsb + 83200000);
  int*   rowp = (int*)(wsb + 83840000);
  int*   cnt  = (int*)(wsb + 83880004);
  int*   csrs = (int*)(wsb + 83920004);
  float* csrv = (float*)(wsb + 84560004);
  unsigned short* Wbih = (unsigned short*)(wsb + 85200004);
  unsigned short* W2t  = (unsigned short*)(wsb + 85224580);

  int eb = (E + 255) / 256;

  hipMemsetAsync(cnt, 0, N_NODES*sizeof(int), stream);
  k_count<<<eb, 256, 0, stream>>>(edst, cnt, E);
  k_scan<<<1, 256, 0, stream>>>(cnt, rowp, N_NODES);
  hipMemsetAsync(cnt, 0, N_NODES*sizeof(int), stream);
  k_fill<<<eb, 256, 0, stream>>>(esrc, edst, eval, rowp, cnt, csrs, csrv, E);
  k_cvtw<<<48, 256, 0, stream>>>(Wih, Wbih, 192*64);
  k_cvtw2<<<48, 256, 0, stream>>>(W2, W2t);

  k_x2h<<<625, 256, 0, stream>>>(x, Z0);
  k_spmm16<<<625, 256, 0, stream>>>(Z0, Z1, rowp, csrs, csrv);
  k_spmm16<<<625, 256, 0, stream>>>(Z1, Z2, rowp, csrs, csrv);
  k_layer1<<<40000, 256, 0, stream>>>(Z0, Z1, Z2, W1, b1, H1b);

  k_spmmC<<<5000, 256, 0, stream>>>(H1b, ZB1, rowp, csrs, csrv);
  k_spmmC<<<5000, 256, 0, stream>>>(ZB1, ZB2, rowp, csrs, csrv);
  k_layer2m<<<2500, 256, 0, stream>>>(H1b, ZB1, ZB2, W2t, b2, OUT2b);

  k_gx<<<2500, 256, 0, stream>>>(OUT2b, Wbih, bih, GX);
  k_gru<<<313, 512, 0, stream>>>(GX, Whh, bhh, Whead, bhead, y);
}

// Round 5
// 355.579 us; speedup vs baseline: 2.5941x; 1.6406x over previous
//
#include <hip/hip_runtime.h>
#include <math.h>

#define N_NODES 10000
#define B_SZ 2
#define T_STEPS 8
#define M_COLS 16
#define BN 20000
#define NM 160000

typedef __attribute__((ext_vector_type(8))) short short8;
typedef __attribute__((ext_vector_type(4))) float f32x4;

__device__ __forceinline__ float b2f(unsigned short u) {
  union { unsigned int i; float f; } x; x.i = ((unsigned int)u) << 16; return x.f;
}
__device__ __forceinline__ unsigned short f2b(float f) {
  unsigned int x = __float_as_uint(f);
  return (unsigned short)((x + 0x7fffu + ((x >> 16) & 1u)) >> 16);
}
__device__ __forceinline__ float sigm(float x) {
  return 1.f / (1.f + __expf(-x));      // x->-inf: exp->inf -> 0 (no NaN)
}
__device__ __forceinline__ float tanhfast(float x) {
  float xm = fmaxf(x, -15.f);           // avoid inf/inf NaN; tanh(-15) == -1 in fp32
  float e = __expf(-2.f * xm);
  return (1.f - e) / (1.f + e);
}

// ---------------- CSR build ----------------
__global__ __launch_bounds__(256) void k_count(const int* __restrict__ dst, int* __restrict__ cnt, int E) {
  int e = blockIdx.x*256 + threadIdx.x;
  if (e < E) atomicAdd(&cnt[dst[e]], 1);
}

__global__ __launch_bounds__(256) void k_scan(const int* __restrict__ cnt, int* __restrict__ rowp, int n) {
  const int K = 40;
  int t = threadIdx.x;
  int beg = t*K;
  int end = beg + K < n ? beg + K : n;
  int s = 0;
  for (int i = beg; i < end; ++i) s += cnt[i];
  int lane = t & 63, w = t >> 6;
  int v = s;
#pragma unroll
  for (int off = 1; off < 64; off <<= 1) {
    int u = __shfl_up(v, off, 64);
    if (lane >= off) v += u;
  }
  __shared__ int wsum[4];
  if (lane == 63) wsum[w] = v;
  __syncthreads();
  int woff = 0;
  for (int i = 0; i < w; ++i) woff += wsum[i];
  int run = woff + v - s;
  for (int i = beg; i < end; ++i) { rowp[i] = run; run += cnt[i]; }
  if (t == 255) rowp[n] = run;
}

__global__ __launch_bounds__(256) void k_fill(const int* __restrict__ src, const int* __restrict__ dst,
                                              const float* __restrict__ val, const int* __restrict__ rowp,
                                              int* __restrict__ cur, int* __restrict__ csrs,
                                              float* __restrict__ csrv, int E) {
  int e = blockIdx.x*256 + threadIdx.x;
  if (e >= E) return;
  int d = dst[e];
  int p = atomicAdd(&cur[d], 1);
  int slot = rowp[d] + p;
  csrs[slot] = src[e];
  csrv[slot] = val[e];
}

__global__ __launch_bounds__(256) void k_cvtw(const float* __restrict__ W, unsigned short* __restrict__ Wb, int n) {
  int i = blockIdx.x*256 + threadIdx.x;
  if (i < n) Wb[i] = f2b(W[i]);
}

// Wt[p][c][k] = W2[p][k][c]  (bf16)
__global__ __launch_bounds__(256) void k_cvtw2(const float* __restrict__ W2, unsigned short* __restrict__ Wt) {
  int i = blockIdx.x*256 + threadIdx.x;
  if (i >= 3*64*64) return;
  int p = i >> 12, rem = i & 4095, c = rem >> 6, k = rem & 63;
  Wt[i] = f2b(W2[p*4096 + k*64 + c]);
}

// hi/lo bf16 split of Whh (fp32 ~= hi + lo)
__global__ __launch_bounds__(256) void k_cvtsplit(const float* __restrict__ W,
                                                  unsigned short* __restrict__ Whi,
                                                  unsigned short* __restrict__ Wlo, int n) {
  int i = blockIdx.x*256 + threadIdx.x;
  if (i >= n) return;
  float v = W[i];
  unsigned short h = f2b(v);
  Whi[i] = h;
  Wlo[i] = f2b(v - b2f(h));
}

// ---------------- layer 1 ----------------
__global__ __launch_bounds__(256) void k_x2h(const float* __restrict__ x, float* __restrict__ Z0) {
  int i = blockIdx.x*256 + threadIdx.x;
  if (i >= NM) return;
  int n = i >> 4, m = i & 15;
  int b = m >> 3, t = m & 7;
  Z0[i] = x[b*(N_NODES*T_STEPS) + n*T_STEPS + t];
}

__global__ __launch_bounds__(256) void k_spmm16(const float* __restrict__ Zin, float* __restrict__ Zout,
                                                const int* __restrict__ rowp, const int* __restrict__ csrs,
                                                const float* __restrict__ csrv) {
  int i = blockIdx.x*256 + threadIdx.x;
  if (i >= NM) return;
  int n = i >> 4, m = i & 15;
  int s = rowp[n], e = rowp[n+1];
  float acc = 0.f;
  for (int k = s; k < e; ++k)
    acc = fmaf(csrv[k], Zin[csrs[k]*16 + m], acc);
  Zout[i] = acc;
}

__global__ __launch_bounds__(256) void k_layer1(const float* __restrict__ Z0, const float* __restrict__ Z1,
                                                const float* __restrict__ Z2, const float* __restrict__ W1,
                                                const float* __restrict__ b1, unsigned short* __restrict__ H1b) {
  int i = blockIdx.x*256 + threadIdx.x;
  int c = i & 63, nm = i >> 6;
  float v = fmaf(Z0[nm], W1[c], fmaf(Z1[nm], W1[64+c], fmaf(Z2[nm], W1[128+c], b1[c])));
  H1b[i] = f2b(v > 0.f ? v : 0.f);
}

// ---------------- layer 2 ----------------
__global__ __launch_bounds__(256) void k_spmmC(const unsigned short* __restrict__ Zin,
                                               unsigned short* __restrict__ Zout,
                                               const int* __restrict__ rowp, const int* __restrict__ csrs,
                                               const float* __restrict__ csrv) {
  int c = blockIdx.x / 625;                       // chunk-major dispatch
  int n = (blockIdx.x % 625)*16 + (threadIdx.x >> 4);
  int l = threadIdx.x & 15;
  int off = c*128 + l*8;
  int s = rowp[n], e = rowp[n+1];
  float acc[8] = {0,0,0,0,0,0,0,0};
  for (int k = s; k < e; ++k) {
    int src = csrs[k];
    float v = csrv[k];
    union { uint4 u; unsigned short s[8]; } z;
    z.u = *(const uint4*)(Zin + (size_t)src*1024 + off);
#pragma unroll
    for (int j = 0; j < 8; ++j) acc[j] = fmaf(v, b2f(z.s[j]), acc[j]);
  }
  union { uint4 u; unsigned short s[8]; } o;
#pragma unroll
  for (int j = 0; j < 8; ++j) o.s[j] = f2b(acc[j]);
  *(uint4*)(Zout + (size_t)n*1024 + off) = o.u;
}

// MFMA layer 2
__global__ __launch_bounds__(256) void k_layer2m(const unsigned short* __restrict__ H1b,
                                                 const unsigned short* __restrict__ Z1b,
                                                 const unsigned short* __restrict__ Z2b,
                                                 const unsigned short* __restrict__ Wt,
                                                 const float* __restrict__ b2,
                                                 unsigned short* __restrict__ OUT2b) {
  int wid = blockIdx.x*4 + (threadIdx.x >> 6);    // 0..9999
  int lane = threadIdx.x & 63;
  int lr = lane & 15, hi = lane >> 4;
  int rowbase = wid*16;
  const short* A0 = (const short*)H1b + (size_t)(rowbase + lr)*64;
  const short* A1 = (const short*)Z1b + (size_t)(rowbase + lr)*64;
  const short* A2 = (const short*)Z2b + (size_t)(rowbase + lr)*64;
  short8 a[3][2];
  a[0][0] = *(const short8*)(A0 + hi*8); a[0][1] = *(const short8*)(A0 + 32 + hi*8);
  a[1][0] = *(const short8*)(A1 + hi*8); a[1][1] = *(const short8*)(A1 + 32 + hi*8);
  a[2][0] = *(const short8*)(A2 + hi*8); a[2][1] = *(const short8*)(A2 + 32 + hi*8);
  const short* Bp = (const short*)Wt;
  f32x4 acc[4];
#pragma unroll
  for (int ct = 0; ct < 4; ++ct) {
    int col = ct*16 + lr;
    f32x4 c = {0.f, 0.f, 0.f, 0.f};
#pragma unroll
    for (int p = 0; p < 3; ++p) {
      short8 b0 = *(const short8*)(Bp + p*4096 + col*64 + hi*8);
      short8 b1 = *(const short8*)(Bp + p*4096 + col*64 + 32 + hi*8);
      c = __builtin_amdgcn_mfma_f32_16x16x32_bf16(a[p][0], b0, c, 0, 0, 0);
      c = __builtin_amdgcn_mfma_f32_16x16x32_bf16(a[p][1], b1, c, 0, 0, 0);
    }
    acc[ct] = c;
  }
#pragma unroll
  for (int ct = 0; ct < 4; ++ct) {
    int col = ct*16 + lr;
    float bb = b2[col];
#pragma unroll
    for (int r = 0; r < 4; ++r) {
      int nm = rowbase + hi*4 + r;
      int n = nm >> 4, m = nm & 15;
      int bi = m >> 3, t = m & 7;
      float v = acc[ct][r] + bb;
      OUT2b[((size_t)((t*2 + bi)*N_NODES + n))*64 + col] = f2b(v > 0.f ? v : 0.f);
    }
  }
}

// ---------------- GRU ----------------
// GX = x @ W_ih^T + b_ih (bf16 MFMA), stored PRE-PACKED per (rowtile, lane):
// GX[((t*1250 + b*625 + ntile)*64 + lane)*48 + ct*4 + r]  — identical lane
// mapping to k_gru's MFMA C-layout, so k_gru reads 6 contiguous dwordx4.
__global__ __launch_bounds__(256) void k_gx(const unsigned short* __restrict__ A,
                                            const unsigned short* __restrict__ Bw,
                                            const float* __restrict__ bih,
                                            unsigned short* __restrict__ GX) {
  int wid = blockIdx.x*4 + (threadIdx.x >> 6);    // rowtile over [t][b][n]
  int lane = threadIdx.x & 63;
  int lr = lane & 15, hi = lane >> 4;
  int rowbase = wid*16;
  const short* Ap = (const short*)A;
  const short* Bp = (const short*)Bw;
  short8 a0 = *(const short8*)(Ap + (size_t)(rowbase + lr)*64 + hi*8);
  short8 a1 = *(const short8*)(Ap + (size_t)(rowbase + lr)*64 + 32 + hi*8);
  f32x4 acc[12];
#pragma unroll
  for (int ct = 0; ct < 12; ++ct) {
    int col = ct*16 + lr;
    short8 b0 = *(const short8*)(Bp + col*64 + hi*8);
    short8 b1 = *(const short8*)(Bp + col*64 + 32 + hi*8);
    f32x4 c = {0.f, 0.f, 0.f, 0.f};
    c = __builtin_amdgcn_mfma_f32_16x16x32_bf16(a0, b0, c, 0, 0, 0);
    c = __builtin_amdgcn_mfma_f32_16x16x32_bf16(a1, b1, c, 0, 0, 0);
    acc[ct] = c;
  }
  int tb = wid / 625, ntile = wid % 625;
  int t = tb >> 1, b = tb & 1;
  unsigned short* dst = GX + ((size_t)((t*1250 + b*625 + ntile)*64 + lane))*48;
  union { uint4 v[6]; unsigned short s[48]; } buf;
#pragma unroll
  for (int ct = 0; ct < 12; ++ct) {
    float bb = bih[ct*16 + lr];
#pragma unroll
    for (int r = 0; r < 4; ++r) buf.s[ct*4 + r] = f2b(acc[ct][r] + bb);
  }
#pragma unroll
  for (int q = 0; q < 6; ++q) ((uint4*)dst)[q] = buf.v[q];
}

// Wave-owned MFMA GRU: one wave = 16 rows through all 8 steps; no barriers.
// gh = hi(h)@hi(W) + hi(h)@lo(W) + lo(h)@hi(W)  (fp32-accurate, 72 MFMA/step).
// h state in registers (hreg[4][4], constant-indexed); LDS only redistributes
// h into next step's A-fragment (stride-68 pad -> 2-way free bank pattern).
__global__ __launch_bounds__(256, 1) void k_gru(const unsigned short* __restrict__ GX,
                                                const unsigned short* __restrict__ Whi,
                                                const unsigned short* __restrict__ Wlo,
                                                const float* __restrict__ bhh,
                                                const float* __restrict__ Whead,
                                                const float* __restrict__ bhead,
                                                float* __restrict__ y) {
  __shared__ float hs[4][16][68];
  int w = threadIdx.x >> 6;
  int lane = threadIdx.x & 63;
  int lr = lane & 15, hi4 = lane >> 4;
  int R = blockIdx.x*4 + w;                       // rowtile 0..1249 (wave-uniform)
  if (R >= 1250) return;

  // B fragments (stationary across steps): 12 col-tiles x 2 K-chunks x {hi,lo}
  const short* Wh = (const short*)Whi;
  const short* Wl = (const short*)Wlo;
  short8 bh[12][2], bl[12][2];
#pragma unroll
  for (int ct = 0; ct < 12; ++ct) {
    int col = ct*16 + lr;
#pragma unroll
    for (int kc = 0; kc < 2; ++kc) {
      bh[ct][kc] = *(const short8*)(Wh + col*64 + kc*32 + hi4*8);
      bl[ct][kc] = *(const short8*)(Wl + col*64 + kc*32 + hi4*8);
    }
  }
  float bR[4], bZ[4], bN[4];
#pragma unroll
  for (int cr = 0; cr < 4; ++cr) {
    bR[cr] = bhh[cr*16 + lr];
    bZ[cr] = bhh[64 + cr*16 + lr];
    bN[cr] = bhh[128 + cr*16 + lr];
  }
  // zero h state (regs + LDS redistribution buffer)
  float hreg[4][4];
#pragma unroll
  for (int cr = 0; cr < 4; ++cr)
#pragma unroll
    for (int j = 0; j < 4; ++j) hreg[cr][j] = 0.f;
#pragma unroll
  for (int j = 0; j < 17; ++j) hs[w][lr][hi4*17 + j] = 0.f;

  const unsigned short* gxp = GX + ((size_t)R*64 + lane)*48;

#pragma unroll 1
  for (int t = 0; t < 8; ++t) {
    // A fragments from hs, split hi/lo
    short8 ahi[2], alo[2];
#pragma unroll
    for (int kc = 0; kc < 2; ++kc) {
      float hv[8];
      float4 v0 = *(const float4*)&hs[w][lr][kc*32 + hi4*8];
      float4 v1 = *(const float4*)&hs[w][lr][kc*32 + hi4*8 + 4];
      hv[0]=v0.x; hv[1]=v0.y; hv[2]=v0.z; hv[3]=v0.w;
      hv[4]=v1.x; hv[5]=v1.y; hv[6]=v1.z; hv[7]=v1.w;
      union { short8 v; unsigned short s[8]; } uh, ul;
#pragma unroll
      for (int j = 0; j < 8; ++j) {
        unsigned short hb = f2b(hv[j]);
        uh.s[j] = hb;
        ul.s[j] = f2b(hv[j] - b2f(hb));
      }
      ahi[kc] = uh.v; alo[kc] = ul.v;
    }
    // gh accumulators
    f32x4 aR[4], aZ[4], aN[4];
#pragma unroll
    for (int cr = 0; cr < 4; ++cr) {
      f32x4 zz = {0.f,0.f,0.f,0.f};
      aR[cr] = zz; aZ[cr] = zz; aN[cr] = zz;
    }
#pragma unroll
    for (int cr = 0; cr < 4; ++cr) {
#pragma unroll
      for (int kc = 0; kc < 2; ++kc) {
        aR[cr] = __builtin_amdgcn_mfma_f32_16x16x32_bf16(ahi[kc], bh[cr][kc],   aR[cr], 0, 0, 0);
        aR[cr] = __builtin_amdgcn_mfma_f32_16x16x32_bf16(ahi[kc], bl[cr][kc],   aR[cr], 0, 0, 0);
        aR[cr] = __builtin_amdgcn_mfma_f32_16x16x32_bf16(alo[kc], bh[cr][kc],   aR[cr], 0, 0, 0);
        aZ[cr] = __builtin_amdgcn_mfma_f32_16x16x32_bf16(ahi[kc], bh[cr+4][kc], aZ[cr], 0, 0, 0);
        aZ[cr] = __builtin_amdgcn_mfma_f32_16x16x32_bf16(ahi[kc], bl[cr+4][kc], aZ[cr], 0, 0, 0);
        aZ[cr] = __builtin_amdgcn_mfma_f32_16x16x32_bf16(alo[kc], bh[cr+4][kc], aZ[cr], 0, 0, 0);
        aN[cr] = __builtin_amdgcn_mfma_f32_16x16x32_bf16(ahi[kc], bh[cr+8][kc], aN[cr], 0, 0, 0);
        aN[cr] = __builtin_amdgcn_mfma_f32_16x16x32_bf16(ahi[kc], bl[cr+8][kc], aN[cr], 0, 0, 0);
        aN[cr] = __builtin_amdgcn_mfma_f32_16x16x32_bf16(alo[kc], bh[cr+8][kc], aN[cr], 0, 0, 0);
      }
    }
    // gate pre-activations from GX (pre-packed, 6 x dwordx4)
    const unsigned short* g = gxp + (size_t)t*3840000;   // 1250*64*48
    union { uint4 v[6]; unsigned short s[48]; } gx;
#pragma unroll
    for (int q = 0; q < 6; ++q) gx.v[q] = ((const uint4*)g)[q];
    // update (fully in-register)
#pragma unroll
    for (int cr = 0; cr < 4; ++cr) {
#pragma unroll
      for (int j = 0; j < 4; ++j) {
        float r = sigm(b2f(gx.s[cr*4 + j])      + aR[cr][j] + bR[cr]);
        float z = sigm(b2f(gx.s[(cr+4)*4 + j])  + aZ[cr][j] + bZ[cr]);
        float nn = tanhfast(b2f(gx.s[(cr+8)*4 + j]) + r*(aN[cr][j] + bN[cr]));
        hreg[cr][j] = (1.f - z)*nn + z*hreg[cr][j];
      }
    }
    // redistribute h for next step's A-fragment
#pragma unroll
    for (int cr = 0; cr < 4; ++cr)
#pragma unroll
      for (int j = 0; j < 4; ++j)
        hs[w][hi4*4 + j][cr*16 + lr] = hreg[cr][j];
  }
  // head: y[row] = sum_col h * Whead + b
  float wv[4];
#pragma unroll
  for (int cr = 0; cr < 4; ++cr) wv[cr] = Whead[cr*16 + lr];
#pragma unroll
  for (int j = 0; j < 4; ++j) {
    float p = 0.f;
#pragma unroll
    for (int cr = 0; cr < 4; ++cr) p = fmaf(hreg[cr][j], wv[cr], p);
    p += __shfl_xor(p, 1, 64);
    p += __shfl_xor(p, 2, 64);
    p += __shfl_xor(p, 4, 64);
    p += __shfl_xor(p, 8, 64);
    if (lr == 0) y[R*16 + hi4*4 + j] = p + bhead[0];
  }
}

extern "C" void kernel_launch(void* const* d_in, const int* in_sizes, int n_in,
                              void* d_out, int out_size, void* d_ws, size_t ws_size,
                              hipStream_t stream) {
  const float* x    = (const float*)d_in[0];
  const int*   esrc = (const int*)d_in[1];
  const int*   edst = (const int*)d_in[2];
  const float* eval = (const float*)d_in[3];
  const float* W1   = (const float*)d_in[4];
  const float* b1   = (const float*)d_in[5];
  const float* W2   = (const float*)d_in[6];
  const float* b2   = (const float*)d_in[7];
  const float* Wih  = (const float*)d_in[8];
  const float* Whh  = (const float*)d_in[9];
  const float* bih  = (const float*)d_in[10];
  const float* bhh  = (const float*)d_in[11];
  const float* Whead= (const float*)d_in[12];
  const float* bhead= (const float*)d_in[13];
  int E = in_sizes[1];
  float* y = (float*)d_out;

  char* wsb = (char*)d_ws;
  unsigned short* H1b   = (unsigned short*)(wsb + 0);
  unsigned short* GX    = (unsigned short*)(wsb + 0);          // aliases H1b/ZB1/ZB2
  unsigned short* ZB1   = (unsigned short*)(wsb + 20480000);
  unsigned short* ZB2   = (unsigned short*)(wsb + 40960000);
  unsigned short* OUT2b = (unsigned short*)(wsb + 61440000);
  float* Z0   = (float*)(wsb + 81920000);
  float* Z1   = (float*)(wsb + 82560000);
  float* Z2   = (float*)(wsb + 83200000);
  int*   rowp = (int*)(wsb + 83840000);
  int*   cnt  = (int*)(wsb + 83880064);
  int*   csrs = (int*)(wsb + 83920064);
  float* csrv = (float*)(wsb + 84560064);
  unsigned short* Wbih = (unsigned short*)(wsb + 85200064);
  unsigned short* W2t  = (unsigned short*)(wsb + 85224640);
  unsigned short* Whhi = (unsigned short*)(wsb + 85249280);
  unsigned short* Whlo = (unsigned short*)(wsb + 85273856);

  int eb = (E + 255) / 256;

  hipMemsetAsync(cnt, 0, N_NODES*sizeof(int), stream);
  k_count<<<eb, 256, 0, stream>>>(edst, cnt, E);
  k_scan<<<1, 256, 0, stream>>>(cnt, rowp, N_NODES);
  hipMemsetAsync(cnt, 0, N_NODES*sizeof(int), stream);
  k_fill<<<eb, 256, 0, stream>>>(esrc, edst, eval, rowp, cnt, csrs, csrv, E);
  k_cvtw<<<48, 256, 0, stream>>>(Wih, Wbih, 192*64);
  k_cvtw2<<<48, 256, 0, stream>>>(W2, W2t);
  k_cvtsplit<<<48, 256, 0, stream>>>(Whh, Whhi, Whlo, 192*64);

  k_x2h<<<625, 256, 0, stream>>>(x, Z0);
  k_spmm16<<<625, 256, 0, stream>>>(Z0, Z1, rowp, csrs, csrv);
  k_spmm16<<<625, 256, 0, stream>>>(Z1, Z2, rowp, csrs, csrv);
  k_layer1<<<40000, 256, 0, stream>>>(Z0, Z1, Z2, W1, b1, H1b);

  k_spmmC<<<5000, 256, 0, stream>>>(H1b, ZB1, rowp, csrs, csrv);
  k_spmmC<<<5000, 256, 0, stream>>>(ZB1, ZB2, rowp, csrs, csrv);
  k_layer2m<<<2500, 256, 0, stream>>>(H1b, ZB1, ZB2, W2t, b2, OUT2b);

  k_gx<<<2500, 256, 0, stream>>>(OUT2b, Wbih, bih, GX);
  k_gru<<<313, 256, 0, stream>>>(GX, Whhi, Whlo, bhh, Whead, bhead, y);
}

// Round 6
// 280.583 us; speedup vs baseline: 3.2875x; 1.2673x over previous
//
#include <hip/hip_runtime.h>
#include <math.h>

#define N_NODES 10000
#define B_SZ 2
#define T_STEPS 8
#define M_COLS 16
#define BN 20000
#define NM 160000

typedef __attribute__((ext_vector_type(8))) short short8;
typedef __attribute__((ext_vector_type(4))) float f32x4;

__device__ __forceinline__ float b2f(unsigned short u) {
  union { unsigned int i; float f; } x; x.i = ((unsigned int)u) << 16; return x.f;
}
__device__ __forceinline__ unsigned short f2b(float f) {
  unsigned int x = __float_as_uint(f);
  return (unsigned short)((x + 0x7fffu + ((x >> 16) & 1u)) >> 16);
}
__device__ __forceinline__ float sigm(float x) {
  return 1.f / (1.f + __expf(-x));
}
__device__ __forceinline__ float tanhfast(float x) {
  float xm = fmaxf(x, -15.f);
  float e = __expf(-2.f * xm);
  return (1.f - e) / (1.f + e);
}

// ---------------- CSR build ----------------
__global__ __launch_bounds__(256) void k_count(const int* __restrict__ dst, int* __restrict__ cnt, int E) {
  int e = blockIdx.x*256 + threadIdx.x;
  if (e < E) atomicAdd(&cnt[dst[e]], 1);
}

__global__ __launch_bounds__(256) void k_scan(const int* __restrict__ cnt, int* __restrict__ rowp, int n) {
  const int K = 40;
  int t = threadIdx.x;
  int beg = t*K;
  int end = beg + K < n ? beg + K : n;
  int s = 0;
  for (int i = beg; i < end; ++i) s += cnt[i];
  int lane = t & 63, w = t >> 6;
  int v = s;
#pragma unroll
  for (int off = 1; off < 64; off <<= 1) {
    int u = __shfl_up(v, off, 64);
    if (lane >= off) v += u;
  }
  __shared__ int wsum[4];
  if (lane == 63) wsum[w] = v;
  __syncthreads();
  int woff = 0;
  for (int i = 0; i < w; ++i) woff += wsum[i];
  int run = woff + v - s;
  for (int i = beg; i < end; ++i) { rowp[i] = run; run += cnt[i]; }
  if (t == 255) rowp[n] = run;
}

__global__ __launch_bounds__(256) void k_fill(const int* __restrict__ src, const int* __restrict__ dst,
                                              const float* __restrict__ val, const int* __restrict__ rowp,
                                              int* __restrict__ cur, int* __restrict__ csrs,
                                              float* __restrict__ csrv, int E) {
  int e = blockIdx.x*256 + threadIdx.x;
  if (e >= E) return;
  int d = dst[e];
  int p = atomicAdd(&cur[d], 1);
  int slot = rowp[d] + p;
  csrs[slot] = src[e];
  csrv[slot] = val[e];
}

__global__ __launch_bounds__(256) void k_cvtw(const float* __restrict__ W, unsigned short* __restrict__ Wb, int n) {
  int i = blockIdx.x*256 + threadIdx.x;
  if (i < n) Wb[i] = f2b(W[i]);
}

// Wt[p][c][k] = W2[p][k][c]  (bf16)
__global__ __launch_bounds__(256) void k_cvtw2(const float* __restrict__ W2, unsigned short* __restrict__ Wt) {
  int i = blockIdx.x*256 + threadIdx.x;
  if (i >= 3*64*64) return;
  int p = i >> 12, rem = i & 4095, c = rem >> 6, k = rem & 63;
  Wt[i] = f2b(W2[p*4096 + k*64 + c]);
}

// hi/lo bf16 split of Whh (fp32 ~= hi + lo)
__global__ __launch_bounds__(256) void k_cvtsplit(const float* __restrict__ W,
                                                  unsigned short* __restrict__ Whi,
                                                  unsigned short* __restrict__ Wlo, int n) {
  int i = blockIdx.x*256 + threadIdx.x;
  if (i >= n) return;
  float v = W[i];
  unsigned short h = f2b(v);
  Whi[i] = h;
  Wlo[i] = f2b(v - b2f(h));
}

// ---------------- layer 1 ----------------
__global__ __launch_bounds__(256) void k_x2h(const float* __restrict__ x, float* __restrict__ Z0) {
  int i = blockIdx.x*256 + threadIdx.x;
  if (i >= NM) return;
  int n = i >> 4, m = i & 15;
  int b = m >> 3, t = m & 7;
  Z0[i] = x[b*(N_NODES*T_STEPS) + n*T_STEPS + t];
}

__global__ __launch_bounds__(256) void k_spmm16(const float* __restrict__ Zin, float* __restrict__ Zout,
                                                const int* __restrict__ rowp, const int* __restrict__ csrs,
                                                const float* __restrict__ csrv) {
  int i = blockIdx.x*256 + threadIdx.x;
  if (i >= NM) return;
  int n = i >> 4, m = i & 15;
  int s = rowp[n], e = rowp[n+1];
  float acc = 0.f;
  for (int k = s; k < e; ++k)
    acc = fmaf(csrv[k], Zin[csrs[k]*16 + m], acc);
  Zout[i] = acc;
}

__global__ __launch_bounds__(256) void k_layer1(const float* __restrict__ Z0, const float* __restrict__ Z1,
                                                const float* __restrict__ Z2, const float* __restrict__ W1,
                                                const float* __restrict__ b1, unsigned short* __restrict__ H1b) {
  int i = blockIdx.x*256 + threadIdx.x;
  int c = i & 63, nm = i >> 6;
  float v = fmaf(Z0[nm], W1[c], fmaf(Z1[nm], W1[64+c], fmaf(Z2[nm], W1[128+c], b1[c])));
  H1b[i] = f2b(v > 0.f ? v : 0.f);
}

// ---------------- layer 2 ----------------
// chunked bf16 spmm, XCD-pinned: chunk = blockIdx & 7 -> wg round-robin puts
// each chunk's 2.56 MB gather slab on ONE XCD's L2.
__global__ __launch_bounds__(256) void k_spmmC(const unsigned short* __restrict__ Zin,
                                               unsigned short* __restrict__ Zout,
                                               const int* __restrict__ rowp, const int* __restrict__ csrs,
                                               const float* __restrict__ csrv) {
  int c = blockIdx.x & 7;
  int grp = blockIdx.x >> 3;
  int n = grp*16 + (threadIdx.x >> 4);
  int l = threadIdx.x & 15;
  int off = c*128 + l*8;
  int s = rowp[n], e = rowp[n+1];
  float acc[8] = {0,0,0,0,0,0,0,0};
  for (int k = s; k < e; ++k) {
    int src = csrs[k];
    float v = csrv[k];
    union { uint4 u; unsigned short s[8]; } z;
    z.u = *(const uint4*)(Zin + (size_t)src*1024 + off);
#pragma unroll
    for (int j = 0; j < 8; ++j) acc[j] = fmaf(v, b2f(z.s[j]), acc[j]);
  }
  union { uint4 u; unsigned short s[8]; } o;
#pragma unroll
  for (int j = 0; j < 8; ++j) o.s[j] = f2b(acc[j]);
  *(uint4*)(Zout + (size_t)n*1024 + off) = o.u;
}

// MFMA layer 2
__global__ __launch_bounds__(256) void k_layer2m(const unsigned short* __restrict__ H1b,
                                                 const unsigned short* __restrict__ Z1b,
                                                 const unsigned short* __restrict__ Z2b,
                                                 const unsigned short* __restrict__ Wt,
                                                 const float* __restrict__ b2,
                                                 unsigned short* __restrict__ OUT2b) {
  int wid = blockIdx.x*4 + (threadIdx.x >> 6);
  int lane = threadIdx.x & 63;
  int lr = lane & 15, hi = lane >> 4;
  int rowbase = wid*16;
  const short* A0 = (const short*)H1b + (size_t)(rowbase + lr)*64;
  const short* A1 = (const short*)Z1b + (size_t)(rowbase + lr)*64;
  const short* A2 = (const short*)Z2b + (size_t)(rowbase + lr)*64;
  short8 a[3][2];
  a[0][0] = *(const short8*)(A0 + hi*8); a[0][1] = *(const short8*)(A0 + 32 + hi*8);
  a[1][0] = *(const short8*)(A1 + hi*8); a[1][1] = *(const short8*)(A1 + 32 + hi*8);
  a[2][0] = *(const short8*)(A2 + hi*8); a[2][1] = *(const short8*)(A2 + 32 + hi*8);
  const short* Bp = (const short*)Wt;
  f32x4 acc[4];
#pragma unroll
  for (int ct = 0; ct < 4; ++ct) {
    int col = ct*16 + lr;
    f32x4 c = {0.f, 0.f, 0.f, 0.f};
#pragma unroll
    for (int p = 0; p < 3; ++p) {
      short8 b0 = *(const short8*)(Bp + p*4096 + col*64 + hi*8);
      short8 b1 = *(const short8*)(Bp + p*4096 + col*64 + 32 + hi*8);
      c = __builtin_amdgcn_mfma_f32_16x16x32_bf16(a[p][0], b0, c, 0, 0, 0);
      c = __builtin_amdgcn_mfma_f32_16x16x32_bf16(a[p][1], b1, c, 0, 0, 0);
    }
    acc[ct] = c;
  }
#pragma unroll
  for (int ct = 0; ct < 4; ++ct) {
    int col = ct*16 + lr;
    float bb = b2[col];
#pragma unroll
    for (int r = 0; r < 4; ++r) {
      int nm = rowbase + hi*4 + r;
      int n = nm >> 4, m = nm & 15;
      int bi = m >> 3, t = m & 7;
      float v = acc[ct][r] + bb;
      OUT2b[((size_t)((t*2 + bi)*N_NODES + n))*64 + col] = f2b(v > 0.f ? v : 0.f);
    }
  }
}

// ---------------- fused GRU (x-gates + h-gates + head) ----------------
// One wave owns 32 rows for all 8 steps; no inter-wave sync after setup.
// All weight fragments live in LDS [frag][lane] (16B each -> conflict-free
// ds_read_b128): frags 0-23 Whh_hi, 24-47 Whh_lo, 48-71 Wih.
// gh = hi(h)@hi(W) + hi(h)@lo(W) + lo(h)@hi(W); x-gates accumulated in fp32.
// n-gate x/h parts kept in separate accumulators (r = .. ; n = tanh(nx + r*nh)).
__global__ __launch_bounds__(256, 1) void k_gru(const unsigned short* __restrict__ OUT2b,
                                                const unsigned short* __restrict__ Whhi,
                                                const unsigned short* __restrict__ Whlo,
                                                const unsigned short* __restrict__ Wihb,
                                                const float* __restrict__ bih,
                                                const float* __restrict__ bhh,
                                                const float* __restrict__ Whead,
                                                const float* __restrict__ bhead,
                                                float* __restrict__ y) {
  extern __shared__ char smem[];
  uint4* WF = (uint4*)smem;                     // [72][64] 16B fragments
  float* HSb = (float*)(smem + 73728);          // [4][32*66] h redistribution
  int tid = threadIdx.x;
  for (int idx = tid; idx < 72*64; idx += 256) {
    int f = idx >> 6, ln = idx & 63;
    int lrr = ln & 15, h4r = ln >> 4;
    int g = (f < 24) ? f : ((f < 48) ? f - 24 : f - 48);
    int ct = g >> 1, kc = g & 1;
    const unsigned short* src = (f < 24) ? Whhi : ((f < 48) ? Whlo : Wihb);
    WF[idx] = *(const uint4*)(src + (ct*16 + lrr)*64 + kc*32 + h4r*8);
  }
  int w = tid >> 6, lane = tid & 63;
  int lr = lane & 15, h4 = lane >> 4;
  float* hs = HSb + w*(32*66);
  for (int i = lane; i < 32*66; i += 64) hs[i] = 0.f;
  __syncthreads();                              // WF ready; no barriers after this
  int Wv = blockIdx.x*4 + w;
  if (Wv >= 625) return;
  int base = Wv*32;
  int row0 = base + lr, row1 = base + 16 + lr;
  int b0 = row0 >= N_NODES ? 1 : 0, b1 = row1 >= N_NODES ? 1 : 0;
  int n0 = row0 - b0*N_NODES, n1 = row1 - b1*N_NODES;
  float cR[4], cZ[4], bNi[4], bNh[4];
#pragma unroll
  for (int cr = 0; cr < 4; ++cr) {
    int col = cr*16 + lr;
    cR[cr]  = bih[col] + bhh[col];
    cZ[cr]  = bih[64+col] + bhh[64+col];
    bNi[cr] = bih[128+col];
    bNh[cr] = bhh[128+col];
  }
  float hreg[2][4][4];
#pragma unroll
  for (int rt = 0; rt < 2; ++rt)
#pragma unroll
    for (int cr = 0; cr < 4; ++cr)
#pragma unroll
      for (int j = 0; j < 4; ++j) hreg[rt][cr][j] = 0.f;
  const short* O = (const short*)OUT2b;

#pragma unroll 1
  for (int t = 0; t < 8; ++t) {
    // x A-fragments from OUT2b (L2-resident slice)
    short8 ax[2][2];
    size_t ab0 = ((size_t)((t*2 + b0)*N_NODES + n0))*64;
    size_t ab1 = ((size_t)((t*2 + b1)*N_NODES + n1))*64;
#pragma unroll
    for (int kc = 0; kc < 2; ++kc) {
      ax[0][kc] = *(const short8*)(O + ab0 + kc*32 + h4*8);
      ax[1][kc] = *(const short8*)(O + ab1 + kc*32 + h4*8);
    }
    // h A-fragments from hs, hi/lo split
    short8 ahi[2][2], alo[2][2];
#pragma unroll
    for (int rt = 0; rt < 2; ++rt)
#pragma unroll
      for (int kc = 0; kc < 2; ++kc) {
        const float* hp = hs + (rt*16 + lr)*66 + kc*32 + h4*8;
        float hv[8];
#pragma unroll
        for (int q = 0; q < 4; ++q) {
          float2 v = *(const float2*)(hp + q*2);
          hv[2*q] = v.x; hv[2*q+1] = v.y;
        }
        union { short8 v; unsigned short s[8]; } uh, ul;
#pragma unroll
        for (int j = 0; j < 8; ++j) {
          unsigned short hb = f2b(hv[j]);
          uh.s[j] = hb;
          ul.s[j] = f2b(hv[j] - b2f(hb));
        }
        ahi[rt][kc] = uh.v; alo[rt][kc] = ul.v;
      }
    f32x4 aR[2][4], aZ[2][4], aNx[2][4], aNh[2][4];
#pragma unroll
    for (int rt = 0; rt < 2; ++rt)
#pragma unroll
      for (int cr = 0; cr < 4; ++cr) {
        f32x4 zz = {0.f,0.f,0.f,0.f};
        aR[rt][cr] = zz; aZ[rt][cr] = zz; aNx[rt][cr] = zz; aNh[rt][cr] = zz;
      }
#pragma unroll
    for (int ct = 0; ct < 12; ++ct) {
#pragma unroll
      for (int kc = 0; kc < 2; ++kc) {
        short8 bhi = *(const short8*)&WF[(ct*2 + kc)*64 + lane];
        short8 blo = *(const short8*)&WF[(24 + ct*2 + kc)*64 + lane];
        short8 bx  = *(const short8*)&WF[(48 + ct*2 + kc)*64 + lane];
#pragma unroll
        for (int rt = 0; rt < 2; ++rt) {
          if (ct < 4) {
            aR[rt][ct] = __builtin_amdgcn_mfma_f32_16x16x32_bf16(ax[rt][kc],  bx,  aR[rt][ct], 0, 0, 0);
            aR[rt][ct] = __builtin_amdgcn_mfma_f32_16x16x32_bf16(ahi[rt][kc], bhi, aR[rt][ct], 0, 0, 0);
            aR[rt][ct] = __builtin_amdgcn_mfma_f32_16x16x32_bf16(ahi[rt][kc], blo, aR[rt][ct], 0, 0, 0);
            aR[rt][ct] = __builtin_amdgcn_mfma_f32_16x16x32_bf16(alo[rt][kc], bhi, aR[rt][ct], 0, 0, 0);
          } else if (ct < 8) {
            int cc = ct - 4;
            aZ[rt][cc] = __builtin_amdgcn_mfma_f32_16x16x32_bf16(ax[rt][kc],  bx,  aZ[rt][cc], 0, 0, 0);
            aZ[rt][cc] = __builtin_amdgcn_mfma_f32_16x16x32_bf16(ahi[rt][kc], bhi, aZ[rt][cc], 0, 0, 0);
            aZ[rt][cc] = __builtin_amdgcn_mfma_f32_16x16x32_bf16(ahi[rt][kc], blo, aZ[rt][cc], 0, 0, 0);
            aZ[rt][cc] = __builtin_amdgcn_mfma_f32_16x16x32_bf16(alo[rt][kc], bhi, aZ[rt][cc], 0, 0, 0);
          } else {
            int cc = ct - 8;
            aNx[rt][cc] = __builtin_amdgcn_mfma_f32_16x16x32_bf16(ax[rt][kc],  bx,  aNx[rt][cc], 0, 0, 0);
            aNh[rt][cc] = __builtin_amdgcn_mfma_f32_16x16x32_bf16(ahi[rt][kc], bhi, aNh[rt][cc], 0, 0, 0);
            aNh[rt][cc] = __builtin_amdgcn_mfma_f32_16x16x32_bf16(ahi[rt][kc], blo, aNh[rt][cc], 0, 0, 0);
            aNh[rt][cc] = __builtin_amdgcn_mfma_f32_16x16x32_bf16(alo[rt][kc], bhi, aNh[rt][cc], 0, 0, 0);
          }
        }
      }
    }
    // gate nonlinearity + h update (in-register), then redistribute via LDS
#pragma unroll
    for (int rt = 0; rt < 2; ++rt)
#pragma unroll
      for (int cr = 0; cr < 4; ++cr)
#pragma unroll
        for (int j = 0; j < 4; ++j) {
          float r = sigm(aR[rt][cr][j] + cR[cr]);
          float z = sigm(aZ[rt][cr][j] + cZ[cr]);
          float nn = tanhfast(aNx[rt][cr][j] + bNi[cr] + r*(aNh[rt][cr][j] + bNh[cr]));
          float hv = (1.f - z)*nn + z*hreg[rt][cr][j];
          hreg[rt][cr][j] = hv;
          hs[(rt*16 + h4*4 + j)*66 + cr*16 + lr] = hv;
        }
  }
  // head
  float wv[4];
#pragma unroll
  for (int cr = 0; cr < 4; ++cr) wv[cr] = Whead[cr*16 + lr];
#pragma unroll
  for (int rt = 0; rt < 2; ++rt)
#pragma unroll
    for (int j = 0; j < 4; ++j) {
      float p = 0.f;
#pragma unroll
      for (int cr = 0; cr < 4; ++cr) p = fmaf(hreg[rt][cr][j], wv[cr], p);
      p += __shfl_xor(p, 1, 64);
      p += __shfl_xor(p, 2, 64);
      p += __shfl_xor(p, 4, 64);
      p += __shfl_xor(p, 8, 64);
      if (lr == 0) y[base + rt*16 + h4*4 + j] = p + bhead[0];
    }
}

extern "C" void kernel_launch(void* const* d_in, const int* in_sizes, int n_in,
                              void* d_out, int out_size, void* d_ws, size_t ws_size,
                              hipStream_t stream) {
  const float* x    = (const float*)d_in[0];
  const int*   esrc = (const int*)d_in[1];
  const int*   edst = (const int*)d_in[2];
  const float* eval = (const float*)d_in[3];
  const float* W1   = (const float*)d_in[4];
  const float* b1   = (const float*)d_in[5];
  const float* W2   = (const float*)d_in[6];
  const float* b2   = (const float*)d_in[7];
  const float* Wih  = (const float*)d_in[8];
  const float* Whh  = (const float*)d_in[9];
  const float* bih  = (const float*)d_in[10];
  const float* bhh  = (const float*)d_in[11];
  const float* Whead= (const float*)d_in[12];
  const float* bhead= (const float*)d_in[13];
  int E = in_sizes[1];
  float* y = (float*)d_out;

  char* wsb = (char*)d_ws;
  unsigned short* H1b   = (unsigned short*)(wsb + 0);
  unsigned short* ZB1   = (unsigned short*)(wsb + 20480000);
  unsigned short* ZB2   = (unsigned short*)(wsb + 40960000);
  unsigned short* OUT2b = (unsigned short*)(wsb + 61440000);
  float* Z0   = (float*)(wsb + 81920000);
  float* Z1   = (float*)(wsb + 82560000);
  float* Z2   = (float*)(wsb + 83200000);
  int*   rowp = (int*)(wsb + 83840000);
  int*   cnt  = (int*)(wsb + 83880064);
  int*   csrs = (int*)(wsb + 83920064);
  float* csrv = (float*)(wsb + 84560064);
  unsigned short* Wbih = (unsigned short*)(wsb + 85200064);
  unsigned short* W2t  = (unsigned short*)(wsb + 85224640);
  unsigned short* Whhi = (unsigned short*)(wsb + 85249280);
  unsigned short* Whlo = (unsigned short*)(wsb + 85273856);

  int eb = (E + 255) / 256;

  hipMemsetAsync(cnt, 0, N_NODES*sizeof(int), stream);
  k_count<<<eb, 256, 0, stream>>>(edst, cnt, E);
  k_scan<<<1, 256, 0, stream>>>(cnt, rowp, N_NODES);
  hipMemsetAsync(cnt, 0, N_NODES*sizeof(int), stream);
  k_fill<<<eb, 256, 0, stream>>>(esrc, edst, eval, rowp, cnt, csrs, csrv, E);
  k_cvtw<<<48, 256, 0, stream>>>(Wih, Wbih, 192*64);
  k_cvtw2<<<48, 256, 0, stream>>>(W2, W2t);
  k_cvtsplit<<<48, 256, 0, stream>>>(Whh, Whhi, Whlo, 192*64);

  k_x2h<<<625, 256, 0, stream>>>(x, Z0);
  k_spmm16<<<625, 256, 0, stream>>>(Z0, Z1, rowp, csrs, csrv);
  k_spmm16<<<625, 256, 0, stream>>>(Z1, Z2, rowp, csrs, csrv);
  k_layer1<<<40000, 256, 0, stream>>>(Z0, Z1, Z2, W1, b1, H1b);

  k_spmmC<<<5000, 256, 0, stream>>>(H1b, ZB1, rowp, csrs, csrv);
  k_spmmC<<<5000, 256, 0, stream>>>(ZB1, ZB2, rowp, csrs, csrv);
  k_layer2m<<<2500, 256, 0, stream>>>(H1b, ZB1, ZB2, W2t, b2, OUT2b);

  // fused GRU: 105 KB dynamic LDS (needs the attribute bump past 64 KB)
  const int gru_lds = 73728 + 4*32*66*4;   // 107520 B
  hipFuncSetAttribute((const void*)k_gru, hipFuncAttributeMaxDynamicSharedMemorySize, gru_lds);
  k_gru<<<157, 256, gru_lds, stream>>>(OUT2b, Whhi, Whlo, Wbih, bih, bhh, Whead, bhead, y);
}

// Round 7
// 267.845 us; speedup vs baseline: 3.4438x; 1.0476x over previous
//
#include <hip/hip_runtime.h>
#include <math.h>

#define N_NODES 10000
#define B_SZ 2
#define T_STEPS 8
#define M_COLS 16
#define BN 20000
#define NM 160000

typedef __attribute__((ext_vector_type(8))) short short8;
typedef __attribute__((ext_vector_type(4))) float f32x4;

__device__ __forceinline__ float b2f(unsigned short u) {
  union { unsigned int i; float f; } x; x.i = ((unsigned int)u) << 16; return x.f;
}
__device__ __forceinline__ unsigned short f2b(float f) {
  unsigned int x = __float_as_uint(f);
  return (unsigned short)((x + 0x7fffu + ((x >> 16) & 1u)) >> 16);
}
__device__ __forceinline__ float sigm(float x) {
  return 1.f / (1.f + __expf(-x));
}
__device__ __forceinline__ float tanhfast(float x) {
  float xm = fmaxf(x, -15.f);
  float e = __expf(-2.f * xm);
  return (1.f - e) / (1.f + e);
}

// ---------------- CSR build ----------------
__global__ __launch_bounds__(256) void k_count(const int* __restrict__ dst, int* __restrict__ cnt, int E) {
  int e = blockIdx.x*256 + threadIdx.x;
  if (e < E) atomicAdd(&cnt[dst[e]], 1);
}

__global__ __launch_bounds__(256) void k_scan(const int* __restrict__ cnt, int* __restrict__ rowp, int n) {
  const int K = 40;
  int t = threadIdx.x;
  int beg = t*K;
  int end = beg + K < n ? beg + K : n;
  int s = 0;
  for (int i = beg; i < end; ++i) s += cnt[i];
  int lane = t & 63, w = t >> 6;
  int v = s;
#pragma unroll
  for (int off = 1; off < 64; off <<= 1) {
    int u = __shfl_up(v, off, 64);
    if (lane >= off) v += u;
  }
  __shared__ int wsum[4];
  if (lane == 63) wsum[w] = v;
  __syncthreads();
  int woff = 0;
  for (int i = 0; i < w; ++i) woff += wsum[i];
  int run = woff + v - s;
  for (int i = beg; i < end; ++i) { rowp[i] = run; run += cnt[i]; }
  if (t == 255) rowp[n] = run;
}

__global__ __launch_bounds__(256) void k_fill(const int* __restrict__ src, const int* __restrict__ dst,
                                              const float* __restrict__ val, const int* __restrict__ rowp,
                                              int* __restrict__ cur, int* __restrict__ csrs,
                                              float* __restrict__ csrv, int E) {
  int e = blockIdx.x*256 + threadIdx.x;
  if (e >= E) return;
  int d = dst[e];
  int p = atomicAdd(&cur[d], 1);
  int slot = rowp[d] + p;
  csrs[slot] = src[e];
  csrv[slot] = val[e];
}

// fused weight prep: Wih->bf16, W2 transpose->bf16, Whh hi/lo split (all 12288 elems)
__global__ __launch_bounds__(256) void k_prep(const float* __restrict__ Wih, const float* __restrict__ W2,
                                              const float* __restrict__ Whh,
                                              unsigned short* __restrict__ Wbih,
                                              unsigned short* __restrict__ W2t,
                                              unsigned short* __restrict__ Whi,
                                              unsigned short* __restrict__ Wlo) {
  int i = blockIdx.x*256 + threadIdx.x;
  if (i >= 12288) return;
  Wbih[i] = f2b(Wih[i]);
  int p = i >> 12, rem = i & 4095, c = rem >> 6, k = rem & 63;
  W2t[i] = f2b(W2[p*4096 + k*64 + c]);
  float v = Whh[i];
  unsigned short h = f2b(v);
  Whi[i] = h;
  Wlo[i] = f2b(v - b2f(h));
}

// ---------------- layer 1 ----------------
__global__ __launch_bounds__(256) void k_x2h(const float* __restrict__ x, float* __restrict__ Z0) {
  int i = blockIdx.x*256 + threadIdx.x;
  if (i >= NM) return;
  int n = i >> 4, m = i & 15;
  int b = m >> 3, t = m & 7;
  Z0[i] = x[b*(N_NODES*T_STEPS) + n*T_STEPS + t];
}

__global__ __launch_bounds__(256) void k_spmm16(const float* __restrict__ Zin, float* __restrict__ Zout,
                                                const int* __restrict__ rowp, const int* __restrict__ csrs,
                                                const float* __restrict__ csrv) {
  int i = blockIdx.x*256 + threadIdx.x;
  if (i >= NM) return;
  int n = i >> 4, m = i & 15;
  int s = rowp[n], e = rowp[n+1];
  float acc = 0.f;
  for (int k = s; k < e; ++k)
    acc = fmaf(csrv[k], Zin[csrs[k]*16 + m], acc);
  Zout[i] = acc;
}

__global__ __launch_bounds__(256) void k_layer1(const float* __restrict__ Z0, const float* __restrict__ Z1,
                                                const float* __restrict__ Z2, const float* __restrict__ W1,
                                                const float* __restrict__ b1, unsigned short* __restrict__ H1b) {
  int i = blockIdx.x*256 + threadIdx.x;
  int c = i & 63, nm = i >> 6;
  float v = fmaf(Z0[nm], W1[c], fmaf(Z1[nm], W1[64+c], fmaf(Z2[nm], W1[128+c], b1[c])));
  H1b[i] = f2b(v > 0.f ? v : 0.f);
}

// ---------------- layer 2 ----------------
// chunked bf16 spmm, XCD-pinned: chunk = blockIdx & 7
__global__ __launch_bounds__(256) void k_spmmC(const unsigned short* __restrict__ Zin,
                                               unsigned short* __restrict__ Zout,
                                               const int* __restrict__ rowp, const int* __restrict__ csrs,
                                               const float* __restrict__ csrv) {
  int c = blockIdx.x & 7;
  int grp = blockIdx.x >> 3;
  int n = grp*16 + (threadIdx.x >> 4);
  int l = threadIdx.x & 15;
  int off = c*128 + l*8;
  int s = rowp[n], e = rowp[n+1];
  float acc[8] = {0,0,0,0,0,0,0,0};
  for (int k = s; k < e; ++k) {
    int src = csrs[k];
    float v = csrv[k];
    union { uint4 u; unsigned short s[8]; } z;
    z.u = *(const uint4*)(Zin + (size_t)src*1024 + off);
#pragma unroll
    for (int j = 0; j < 8; ++j) acc[j] = fmaf(v, b2f(z.s[j]), acc[j]);
  }
  union { uint4 u; unsigned short s[8]; } o;
#pragma unroll
  for (int j = 0; j < 8; ++j) o.s[j] = f2b(acc[j]);
  *(uint4*)(Zout + (size_t)n*1024 + off) = o.u;
}

// MFMA layer 2
__global__ __launch_bounds__(256) void k_layer2m(const unsigned short* __restrict__ H1b,
                                                 const unsigned short* __restrict__ Z1b,
                                                 const unsigned short* __restrict__ Z2b,
                                                 const unsigned short* __restrict__ Wt,
                                                 const float* __restrict__ b2,
                                                 unsigned short* __restrict__ OUT2b) {
  int wid = blockIdx.x*4 + (threadIdx.x >> 6);
  int lane = threadIdx.x & 63;
  int lr = lane & 15, hi = lane >> 4;
  int rowbase = wid*16;
  const short* A0 = (const short*)H1b + (size_t)(rowbase + lr)*64;
  const short* A1 = (const short*)Z1b + (size_t)(rowbase + lr)*64;
  const short* A2 = (const short*)Z2b + (size_t)(rowbase + lr)*64;
  short8 a[3][2];
  a[0][0] = *(const short8*)(A0 + hi*8); a[0][1] = *(const short8*)(A0 + 32 + hi*8);
  a[1][0] = *(const short8*)(A1 + hi*8); a[1][1] = *(const short8*)(A1 + 32 + hi*8);
  a[2][0] = *(const short8*)(A2 + hi*8); a[2][1] = *(const short8*)(A2 + 32 + hi*8);
  const short* Bp = (const short*)Wt;
  f32x4 acc[4];
#pragma unroll
  for (int ct = 0; ct < 4; ++ct) {
    int col = ct*16 + lr;
    f32x4 c = {0.f, 0.f, 0.f, 0.f};
#pragma unroll
    for (int p = 0; p < 3; ++p) {
      short8 b0 = *(const short8*)(Bp + p*4096 + col*64 + hi*8);
      short8 b1 = *(const short8*)(Bp + p*4096 + col*64 + 32 + hi*8);
      c = __builtin_amdgcn_mfma_f32_16x16x32_bf16(a[p][0], b0, c, 0, 0, 0);
      c = __builtin_amdgcn_mfma_f32_16x16x32_bf16(a[p][1], b1, c, 0, 0, 0);
    }
    acc[ct] = c;
  }
#pragma unroll
  for (int ct = 0; ct < 4; ++ct) {
    int col = ct*16 + lr;
    float bb = b2[col];
#pragma unroll
    for (int r = 0; r < 4; ++r) {
      int nm = rowbase + hi*4 + r;
      int n = nm >> 4, m = nm & 15;
      int bi = m >> 3, t = m & 7;
      float v = acc[ct][r] + bb;
      OUT2b[((size_t)((t*2 + bi)*N_NODES + n))*64 + col] = f2b(v > 0.f ? v : 0.f);
    }
  }
}

// ---------------- fused GRU ----------------
// Wave = 16 rows for all 8 steps (1250 wavetiles, 313 blocks -> all CUs busy).
// LDS: Whh hi/lo fragments (48x64x16B) + per-wave h buffer -> 66.5 KB
// => 2 blocks/CU resident = 2 waves/SIMD for latency cover.
// Wih fragments in REGISTERS (24 x short8 = 96 VGPR, constant-indexed).
// gh = hi(h)@hi(W) + hi(h)@lo(W) + lo(h)@hi(W); x-gates fp32-accumulated.
__global__ __launch_bounds__(256, 2) void k_gru(const unsigned short* __restrict__ OUT2b,
                                                const unsigned short* __restrict__ Whhi,
                                                const unsigned short* __restrict__ Whlo,
                                                const unsigned short* __restrict__ Wihb,
                                                const float* __restrict__ bih,
                                                const float* __restrict__ bhh,
                                                const float* __restrict__ Whead,
                                                const float* __restrict__ bhead,
                                                float* __restrict__ y) {
  extern __shared__ char smem[];
  uint4* WF = (uint4*)smem;                     // [48][64]: 0-23 Whh_hi, 24-47 Whh_lo
  float* HSb = (float*)(smem + 49152);          // [4][16*68]
  int tid = threadIdx.x;
  for (int idx = tid; idx < 48*64; idx += 256) {
    int f = idx >> 6, ln = idx & 63;
    int lrr = ln & 15, h4r = ln >> 4;
    int g = (f < 24) ? f : f - 24;
    int ct = g >> 1, kc = g & 1;
    const unsigned short* src = (f < 24) ? Whhi : Whlo;
    WF[idx] = *(const uint4*)(src + (ct*16 + lrr)*64 + kc*32 + h4r*8);
  }
  int w = tid >> 6, lane = tid & 63;
  int lr = lane & 15, h4 = lane >> 4;
  float* hs = HSb + w*(16*68);
  for (int i = lane; i < 16*68; i += 64) hs[i] = 0.f;
  __syncthreads();                              // WF + hs ready; no barriers after
  int Wv = blockIdx.x*4 + w;
  if (Wv >= 1250) return;
  int base = Wv*16;
  int row0 = base + lr;
  int b0 = row0 >= N_NODES ? 1 : 0;
  int n0 = row0 - b0*N_NODES;

  // Wih fragments -> registers (all indices compile-time after unroll)
  const short* Wx = (const short*)Wihb;
  short8 wx[12][2];
#pragma unroll
  for (int ct = 0; ct < 12; ++ct)
#pragma unroll
    for (int kc = 0; kc < 2; ++kc)
      wx[ct][kc] = *(const short8*)(Wx + (ct*16 + lr)*64 + kc*32 + h4*8);

  float cR[4], cZ[4], bNi[4], bNh[4];
#pragma unroll
  for (int cr = 0; cr < 4; ++cr) {
    int col = cr*16 + lr;
    cR[cr]  = bih[col] + bhh[col];
    cZ[cr]  = bih[64+col] + bhh[64+col];
    bNi[cr] = bih[128+col];
    bNh[cr] = bhh[128+col];
  }
  float hreg[4][4];
#pragma unroll
  for (int cr = 0; cr < 4; ++cr)
#pragma unroll
    for (int j = 0; j < 4; ++j) hreg[cr][j] = 0.f;
  const short* O = (const short*)OUT2b;

#pragma unroll 1
  for (int t = 0; t < 8; ++t) {
    // x A-fragments (L2/L3-resident OUT2b slice)
    short8 ax[2];
    size_t ab0 = ((size_t)((t*2 + b0)*N_NODES + n0))*64;
#pragma unroll
    for (int kc = 0; kc < 2; ++kc)
      ax[kc] = *(const short8*)(O + ab0 + kc*32 + h4*8);
    // h A-fragments from LDS, hi/lo split
    short8 ahi[2], alo[2];
#pragma unroll
    for (int kc = 0; kc < 2; ++kc) {
      const float* hp = hs + lr*68 + kc*32 + h4*8;
      float4 v0 = *(const float4*)hp;
      float4 v1 = *(const float4*)(hp + 4);
      float hv[8];
      hv[0]=v0.x; hv[1]=v0.y; hv[2]=v0.z; hv[3]=v0.w;
      hv[4]=v1.x; hv[5]=v1.y; hv[6]=v1.z; hv[7]=v1.w;
      union { short8 v; unsigned short s[8]; } uh, ul;
#pragma unroll
      for (int j = 0; j < 8; ++j) {
        unsigned short hb = f2b(hv[j]);
        uh.s[j] = hb;
        ul.s[j] = f2b(hv[j] - b2f(hb));
      }
      ahi[kc] = uh.v; alo[kc] = ul.v;
    }
    f32x4 aR[4], aZ[4], aNx[4], aNh[4];
#pragma unroll
    for (int cr = 0; cr < 4; ++cr) {
      f32x4 zz = {0.f,0.f,0.f,0.f};
      aR[cr] = zz; aZ[cr] = zz; aNx[cr] = zz; aNh[cr] = zz;
    }
#pragma unroll
    for (int ct = 0; ct < 12; ++ct) {
#pragma unroll
      for (int kc = 0; kc < 2; ++kc) {
        short8 bhi = *(const short8*)&WF[(ct*2 + kc)*64 + lane];
        short8 blo = *(const short8*)&WF[(24 + ct*2 + kc)*64 + lane];
        if (ct < 4) {
          aR[ct] = __builtin_amdgcn_mfma_f32_16x16x32_bf16(ax[kc],  wx[ct][kc], aR[ct], 0, 0, 0);
          aR[ct] = __builtin_amdgcn_mfma_f32_16x16x32_bf16(ahi[kc], bhi,        aR[ct], 0, 0, 0);
          aR[ct] = __builtin_amdgcn_mfma_f32_16x16x32_bf16(ahi[kc], blo,        aR[ct], 0, 0, 0);
          aR[ct] = __builtin_amdgcn_mfma_f32_16x16x32_bf16(alo[kc], bhi,        aR[ct], 0, 0, 0);
        } else if (ct < 8) {
          int cc = ct - 4;
          aZ[cc] = __builtin_amdgcn_mfma_f32_16x16x32_bf16(ax[kc],  wx[ct][kc], aZ[cc], 0, 0, 0);
          aZ[cc] = __builtin_amdgcn_mfma_f32_16x16x32_bf16(ahi[kc], bhi,        aZ[cc], 0, 0, 0);
          aZ[cc] = __builtin_amdgcn_mfma_f32_16x16x32_bf16(ahi[kc], blo,        aZ[cc], 0, 0, 0);
          aZ[cc] = __builtin_amdgcn_mfma_f32_16x16x32_bf16(alo[kc], bhi,        aZ[cc], 0, 0, 0);
        } else {
          int cc = ct - 8;
          aNx[cc] = __builtin_amdgcn_mfma_f32_16x16x32_bf16(ax[kc],  wx[ct][kc], aNx[cc], 0, 0, 0);
          aNh[cc] = __builtin_amdgcn_mfma_f32_16x16x32_bf16(ahi[kc], bhi,        aNh[cc], 0, 0, 0);
          aNh[cc] = __builtin_amdgcn_mfma_f32_16x16x32_bf16(ahi[kc], blo,        aNh[cc], 0, 0, 0);
          aNh[cc] = __builtin_amdgcn_mfma_f32_16x16x32_bf16(alo[kc], bhi,        aNh[cc], 0, 0, 0);
        }
      }
    }
    // gates + h update (in-register), redistribute via LDS
#pragma unroll
    for (int cr = 0; cr < 4; ++cr)
#pragma unroll
      for (int j = 0; j < 4; ++j) {
        float r = sigm(aR[cr][j] + cR[cr]);
        float z = sigm(aZ[cr][j] + cZ[cr]);
        float nn = tanhfast(aNx[cr][j] + bNi[cr] + r*(aNh[cr][j] + bNh[cr]));
        float hv = (1.f - z)*nn + z*hreg[cr][j];
        hreg[cr][j] = hv;
        hs[(h4*4 + j)*68 + cr*16 + lr] = hv;
      }
  }
  // head
  float wv[4];
#pragma unroll
  for (int cr = 0; cr < 4; ++cr) wv[cr] = Whead[cr*16 + lr];
#pragma unroll
  for (int j = 0; j < 4; ++j) {
    float p = 0.f;
#pragma unroll
    for (int cr = 0; cr < 4; ++cr) p = fmaf(hreg[cr][j], wv[cr], p);
    p += __shfl_xor(p, 1, 64);
    p += __shfl_xor(p, 2, 64);
    p += __shfl_xor(p, 4, 64);
    p += __shfl_xor(p, 8, 64);
    if (lr == 0) y[base + h4*4 + j] = p + bhead[0];
  }
}

extern "C" void kernel_launch(void* const* d_in, const int* in_sizes, int n_in,
                              void* d_out, int out_size, void* d_ws, size_t ws_size,
                              hipStream_t stream) {
  const float* x    = (const float*)d_in[0];
  const int*   esrc = (const int*)d_in[1];
  const int*   edst = (const int*)d_in[2];
  const float* eval = (const float*)d_in[3];
  const float* W1   = (const float*)d_in[4];
  const float* b1   = (const float*)d_in[5];
  const float* W2   = (const float*)d_in[6];
  const float* b2   = (const float*)d_in[7];
  const float* Wih  = (const float*)d_in[8];
  const float* Whh  = (const float*)d_in[9];
  const float* bih  = (const float*)d_in[10];
  const float* bhh  = (const float*)d_in[11];
  const float* Whead= (const float*)d_in[12];
  const float* bhead= (const float*)d_in[13];
  int E = in_sizes[1];
  float* y = (float*)d_out;

  char* wsb = (char*)d_ws;
  unsigned short* H1b   = (unsigned short*)(wsb + 0);
  unsigned short* ZB1   = (unsigned short*)(wsb + 20480000);
  unsigned short* ZB2   = (unsigned short*)(wsb + 40960000);
  unsigned short* OUT2b = (unsigned short*)(wsb + 61440000);
  float* Z0   = (float*)(wsb + 81920000);
  float* Z1   = (float*)(wsb + 82560000);
  float* Z2   = (float*)(wsb + 83200000);
  int*   rowp = (int*)(wsb + 83840000);
  int*   cnt  = (int*)(wsb + 83880064);
  int*   csrs = (int*)(wsb + 83920064);
  float* csrv = (float*)(wsb + 84560064);
  unsigned short* Wbih = (unsigned short*)(wsb + 85200064);
  unsigned short* W2t  = (unsigned short*)(wsb + 85224640);
  unsigned short* Whhi = (unsigned short*)(wsb + 85249280);
  unsigned short* Whlo = (unsigned short*)(wsb + 85273856);

  int eb = (E + 255) / 256;

  hipMemsetAsync(cnt, 0, N_NODES*sizeof(int), stream);
  k_count<<<eb, 256, 0, stream>>>(edst, cnt, E);
  k_scan<<<1, 256, 0, stream>>>(cnt, rowp, N_NODES);
  hipMemsetAsync(cnt, 0, N_NODES*sizeof(int), stream);
  k_fill<<<eb, 256, 0, stream>>>(esrc, edst, eval, rowp, cnt, csrs, csrv, E);
  k_prep<<<48, 256, 0, stream>>>(Wih, W2, Whh, Wbih, W2t, Whhi, Whlo);

  k_x2h<<<625, 256, 0, stream>>>(x, Z0);
  k_spmm16<<<625, 256, 0, stream>>>(Z0, Z1, rowp, csrs, csrv);
  k_spmm16<<<625, 256, 0, stream>>>(Z1, Z2, rowp, csrs, csrv);
  k_layer1<<<40000, 256, 0, stream>>>(Z0, Z1, Z2, W1, b1, H1b);

  k_spmmC<<<5000, 256, 0, stream>>>(H1b, ZB1, rowp, csrs, csrv);
  k_spmmC<<<5000, 256, 0, stream>>>(ZB1, ZB2, rowp, csrs, csrv);
  k_layer2m<<<2500, 256, 0, stream>>>(H1b, ZB1, ZB2, W2t, b2, OUT2b);

  const int gru_lds = 49152 + 4*16*68*4;   // 66560 B -> 2 blocks/CU
  hipFuncSetAttribute((const void*)k_gru, hipFuncAttributeMaxDynamicSharedMemorySize, gru_lds);
  k_gru<<<313, 256, gru_lds, stream>>>(OUT2b, Whhi, Whlo, Wbih, bih, bhh, Whead, bhead, y);
}